// Round 6
// baseline (5096.188 us; speedup 1.0000x reference)
//
#include <hip/hip_runtime.h>
#include <stdint.h>

#define NBOX 2000000
#define NCLS 10
#define KPRE 4096
#define KPOST 500
#define NBLK 512
#define NTHR 1024
#define NWAV (NTHR / 64)
#define SEGC 1024        // cand per-segment cap (avg ~156/segment)
#define GCAP 6144        // gathered candidate cap (>= 4096 + p24-bucket size)
#define NMW  (GCAP / 64) // 96 mask words
#define PCAP 131072      // pair cap
#define CSTR 16          // counter stride in u32 (one 64B line per counter)

// ---- workspace layout (bytes) ----
#define OFF_KEYS  ((size_t)0)                              // NBOX*4
#define OFF_CAND  ((size_t)8000000)                        // NBLK*SEGC*8 = 4 MB
#define OFF_PAIRS (OFF_CAND + (size_t)NBLK * SEGC * 8)     // PCAP*4
#define OFF_ARR   (OFF_PAIRS + (size_t)PCAP * 4)           // 32 B * GCAP
#define OFF_LAB   (OFF_ARR + (size_t)GCAP * 32)            // NBOX u8
#define OFF_ZERO  (OFF_LAB + (size_t)NBOX)
// zero region (words): hist0[256] | hist2[256] | hist16[65536] | cntc[NBLK*CSTR] | state[1024]
#define ZW_HIST0  0
#define ZW_HIST2  256
#define ZW_HIST16 512
#define ZW_CNTC   (512 + 65536)
#define ZW_STATE  (ZW_CNTC + NBLK * CSTR)
#define ZERO_WORDS (ZW_STATE + 1024)
#define ZERO_BYTES ((size_t)ZERO_WORDS * 4)

__device__ __forceinline__ uint32_t f2ord(float f) {
  uint32_t b = __float_as_uint(f);
  return (b & 0x80000000u) ? ~b : (b | 0x80000000u);
}
__device__ __forceinline__ float ord2f(uint32_t ord) {
  uint32_t b = (ord & 0x80000000u) ? (ord ^ 0x80000000u) : ~ord;
  return __uint_as_float(b);
}

__device__ __forceinline__ unsigned long long shflx64(unsigned long long v, int mask) {
  union { unsigned long long u; int i[2]; } a; a.u = v;
  a.i[0] = __shfl_xor(a.i[0], mask, 64);
  a.i[1] = __shfl_xor(a.i[1], mask, 64);
  return a.u;
}

// contention-free grid barrier: per-block arrival flags (distinct words, pure stores),
// block 0 aggregates, single release word; relaxed polls + one fence each side.
__device__ __forceinline__ void gbar(uint32_t* flags, uint32_t* release, uint32_t epoch) {
  __syncthreads();  // each wave drains its own vmcnt before s_barrier
  int tid = threadIdx.x;
  if (blockIdx.x == 0) {
    if (tid >= 1 && tid < NBLK) {
      while (__hip_atomic_load(&flags[tid], __ATOMIC_RELAXED, __HIP_MEMORY_SCOPE_AGENT) < epoch)
        __builtin_amdgcn_s_sleep(8);
    }
    __syncthreads();
    if (tid == 0) {
      __threadfence();  // acquire (L2 inv) + release for our own writes
      __hip_atomic_store(release, epoch, __ATOMIC_RELAXED, __HIP_MEMORY_SCOPE_AGENT);
    }
    __syncthreads();
  } else {
    if (tid == 0) {
      __threadfence();  // release: writeback our block's data
      __hip_atomic_store(&flags[blockIdx.x], epoch, __ATOMIC_RELAXED, __HIP_MEMORY_SCOPE_AGENT);
      while (__hip_atomic_load(release, __ATOMIC_RELAXED, __HIP_MEMORY_SCOPE_AGENT) < epoch)
        __builtin_amdgcn_s_sleep(8);
      __threadfence();  // acquire: invalidate stale lines
    }
    __syncthreads();
  }
}

// full-wave (lanes 0..63): bucket of the need-th smallest in h[256] (global or LDS)
__device__ __forceinline__ void wave_bucket(const uint32_t* __restrict__ h, uint32_t need,
                                            uint32_t* bin_out, uint32_t* nd_out) {
  int l = threadIdx.x & 63;
  uint4 h4 = reinterpret_cast<const uint4*>(h)[l];
  uint32_t s = h4.x + h4.y + h4.z + h4.w;
  uint32_t p = s;
  #pragma unroll
  for (int d = 1; d < 64; d <<= 1) {
    uint32_t v = __shfl_up(p, d, 64);
    if (l >= d) p += v;
  }
  uint32_t e0 = p - s, e1 = e0 + h4.x, e2 = e1 + h4.y, e3 = e2 + h4.z, e4 = e3 + h4.w;
  uint32_t eb[5] = {e0, e1, e2, e3, e4};
  uint32_t bin = 0xFFFFFFFFu, nd = 1;
  #pragma unroll
  for (int q = 0; q < 4; ++q)
    if (eb[q] < need && need <= eb[q + 1]) { bin = (uint32_t)(4 * l + q); nd = need - eb[q]; }
  unsigned long long mm = __ballot(bin != 0xFFFFFFFFu);
  int src = mm ? __builtin_ctzll(mm) : 0;
  *bin_out = (uint32_t)__shfl((int)bin, src);
  *nd_out  = (uint32_t)__shfl((int)nd, src);
}

// wave-aggregated dual histogram add: 16-bit bin to global, byte0 to LDS
__device__ __forceinline__ void hist_agg(uint32_t* lh, uint32_t* gh16, uint32_t bin) {
  unsigned long long act = __ballot(1);
  int lane = threadIdx.x & 63;
  unsigned long long rem = act;
  while (rem) {
    int leader = __builtin_ctzll(rem);
    uint32_t lb = __shfl(bin, leader);
    unsigned long long same = __ballot(bin == lb) & act;
    if (lane == leader) {
      uint32_t n = (uint32_t)__builtin_popcountll(same);
      atomicAdd(&gh16[lb], n);
      atomicAdd(&lh[lb >> 8], n);
    }
    rem &= ~same;
  }
}

__device__ __forceinline__ void wave_compact(bool take, unsigned long long key,
                                             uint32_t* counter, unsigned long long* buf,
                                             uint32_t cap) {
  unsigned long long mm = __ballot(take);
  if (take) {
    int lane = threadIdx.x & 63;
    unsigned long long lt = (lane == 0) ? 0ull : (~0ull >> (64 - lane));
    int rank = __builtin_popcountll(mm & lt);
    int leader = __builtin_ctzll(mm);
    uint32_t base = 0;
    if (rank == 0) base = atomicAdd(counter, (uint32_t)__builtin_popcountll(mm));
    base = __shfl(base, leader);
    uint32_t pos = base + (uint32_t)rank;
    if (pos < cap) buf[pos] = key;
  }
}

__device__ __forceinline__ void wave_compact32(bool take, uint32_t key,
                                               uint32_t* counter, uint32_t* buf,
                                               uint32_t cap) {
  unsigned long long mm = __ballot(take);
  if (take) {
    int lane = threadIdx.x & 63;
    unsigned long long lt = (lane == 0) ? 0ull : (~0ull >> (64 - lane));
    int rank = __builtin_popcountll(mm & lt);
    int leader = __builtin_ctzll(mm);
    uint32_t base = 0;
    if (rank == 0) base = atomicAdd(counter, (uint32_t)__builtin_popcountll(mm));
    base = __shfl(base, leader);
    uint32_t pos = base + (uint32_t)rank;
    if (pos < cap) buf[pos] = key;
  }
}

// tree max-of-10 with first-max index (strict > merges == sequential argmax)
__device__ __forceinline__ void tree10(float v0, float v1, float v2, float v3, float v4,
                                       float v5, float v6, float v7, float v8, float v9,
                                       float* mv, int* mi) {
  float b0, b1, b2, b3, b4; int j0, j1, j2, j3, j4;
  if (v1 > v0) { b0 = v1; j0 = 1; } else { b0 = v0; j0 = 0; }
  if (v3 > v2) { b1 = v3; j1 = 3; } else { b1 = v2; j1 = 2; }
  if (v5 > v4) { b2 = v5; j2 = 5; } else { b2 = v4; j2 = 4; }
  if (v7 > v6) { b3 = v7; j3 = 7; } else { b3 = v6; j3 = 6; }
  if (v9 > v8) { b4 = v9; j4 = 9; } else { b4 = v8; j4 = 8; }
  if (b1 > b0) { b0 = b1; j0 = j1; }
  if (b3 > b2) { b2 = b3; j2 = j3; }
  if (b2 > b0) { b0 = b2; j0 = j2; }
  if (b4 > b0) { b0 = b4; j0 = j4; }
  *mv = b0; *mi = j0;
}

// ONE kernel, 512 blocks x 1024 thr, 2 blocks/CU (LDS ~59 KB, VGPR<=64 via launch_bounds):
// A score+hist16 | C compact+hist2 | D p24+selgather | E pairs | F fix(blk0)
__global__ void __launch_bounds__(NTHR, 8) k_all(
    const float* __restrict__ boxes, const float* __restrict__ cls,
    uint32_t* __restrict__ keys, uint8_t* __restrict__ labs,
    unsigned long long* __restrict__ cand, uint32_t* __restrict__ cntc,
    uint32_t* __restrict__ hist0g, uint32_t* __restrict__ hist2g,
    uint32_t* __restrict__ hist16, uint32_t* __restrict__ state,
    float* __restrict__ x1a, float* __restrict__ y1a,
    float* __restrict__ x2a, float* __restrict__ y2a,
    float* __restrict__ vala, int* __restrict__ laba,
    unsigned long long* __restrict__ skg, uint32_t* __restrict__ pairs,
    float* __restrict__ out) {
#pragma clang fp contract(off)
  __shared__ unsigned long long lk[GCAP];   // D: select list | E: staging | F: key cache
  __shared__ unsigned long long validm[NMW], accm[NMW];
  __shared__ uint32_t lh[256];
  __shared__ uint32_t supp[NMW * 2];
  __shared__ uint32_t hsel[256];
  __shared__ uint32_t lsel[512];
  __shared__ unsigned long long kkbuf[512];
  __shared__ uint32_t sp16, sp24, dcnt, dbase, chg, scnt2, sneedS;
  __shared__ unsigned long long spre;
  __shared__ uint32_t orlo, orhi, andlo, andhi;

  int tid = threadIdx.x, blk = blockIdx.x;
  int wid = tid >> 6, lane = tid & 63;
  int gtid = blk * NTHR + tid;
  uint32_t* selcnt = state;
  uint32_t* paircnt = state + 1;
  uint32_t* release = state + 2;
  uint32_t* flags = state + 16;
  const int nvec = NBOX / 4;
  const float4* cp = reinterpret_cast<const float4*>(cls);
  const int pstr = NBOX / 4;

  // ---- A: score (tree max over classes) -> ord keys + labels + byte0/16-bit hists ----
  for (int i = tid; i < 256; i += NTHR) lh[i] = 0;
  __syncthreads();
  for (int v = gtid; v < nvec; v += NBLK * NTHR) {
    float4 x0 = cp[v];
    float4 x1 = cp[pstr * 1 + v];
    float4 x2 = cp[pstr * 2 + v];
    float4 x3 = cp[pstr * 3 + v];
    float4 x4 = cp[pstr * 4 + v];
    float4 x5 = cp[pstr * 5 + v];
    float4 x6 = cp[pstr * 6 + v];
    float4 x7 = cp[pstr * 7 + v];
    float4 x8 = cp[pstr * 8 + v];
    float4 x9 = cp[pstr * 9 + v];
    uint32_t u4[4]; int l4[4];
    float mv; int mi;
    tree10(x0.x, x1.x, x2.x, x3.x, x4.x, x5.x, x6.x, x7.x, x8.x, x9.x, &mv, &mi);
    { float ms = (mv >= 0.1f) ? mv : -1.0f; u4[0] = ~f2ord(ms); l4[0] = mi; }
    tree10(x0.y, x1.y, x2.y, x3.y, x4.y, x5.y, x6.y, x7.y, x8.y, x9.y, &mv, &mi);
    { float ms = (mv >= 0.1f) ? mv : -1.0f; u4[1] = ~f2ord(ms); l4[1] = mi; }
    tree10(x0.z, x1.z, x2.z, x3.z, x4.z, x5.z, x6.z, x7.z, x8.z, x9.z, &mv, &mi);
    { float ms = (mv >= 0.1f) ? mv : -1.0f; u4[2] = ~f2ord(ms); l4[2] = mi; }
    tree10(x0.w, x1.w, x2.w, x3.w, x4.w, x5.w, x6.w, x7.w, x8.w, x9.w, &mv, &mi);
    { float ms = (mv >= 0.1f) ? mv : -1.0f; u4[3] = ~f2ord(ms); l4[3] = mi; }
    #pragma unroll
    for (int q = 0; q < 4; ++q) hist_agg(lh, hist16, u4[q] >> 16);
    reinterpret_cast<uint4*>(keys)[v] = make_uint4(u4[0], u4[1], u4[2], u4[3]);
    uchar4 lb; lb.x = (uint8_t)l4[0]; lb.y = (uint8_t)l4[1];
    lb.z = (uint8_t)l4[2]; lb.w = (uint8_t)l4[3];
    reinterpret_cast<uchar4*>(labs)[v] = lb;
  }
  __syncthreads();
  for (int i = tid; i < 256; i += NTHR) if (lh[i]) atomicAdd(&hist0g[i], lh[i]);
  gbar(flags, release, 1);

  // ---- C: p16 from hist0+hist16 slice; compact own stripe; byte2 hist; sentinels ----
  if (tid < 64) {
    uint32_t b1, nd1, b2, nd2;
    wave_bucket(hist0g, KPRE, &b1, &nd1);
    wave_bucket(hist16 + ((size_t)b1 << 8), nd1, &b2, &nd2);
    if (tid == 0) sp16 = (b1 << 8) | b2;
  }
  for (int i = tid; i < 256; i += NTHR) lh[i] = 0;
  __syncthreads();
  {
    uint32_t p16 = sp16;
    uint32_t* ctr = cntc + blk * CSTR;
    unsigned long long* buf = cand + (size_t)blk * SEGC;
    for (int v = gtid; v < nvec; v += NBLK * NTHR) {
      uint4 kv = reinterpret_cast<const uint4*>(keys)[v];
      uint32_t us[4] = {kv.x, kv.y, kv.z, kv.w};
      #pragma unroll
      for (int q = 0; q < 4; ++q) {
        uint32_t u = us[q];
        uint32_t pref = u >> 16;
        bool take = (pref <= p16);
        unsigned long long key = ((unsigned long long)u << 32) | (uint32_t)(4 * v + q);
        wave_compact(take, key, ctr, buf, SEGC);
        if (take && pref == p16) atomicAdd(&lh[(u >> 8) & 255u], 1u);
      }
    }
    for (int t = gtid; t < GCAP; t += NBLK * NTHR) {
      x1a[t] = 0.0f; y1a[t] = 0.0f; x2a[t] = 0.0f; y2a[t] = 0.0f;
      vala[t] = -1.0f; laba[t] = 0; skg[t] = ~0ull;
    }
  }
  __syncthreads();
  for (int i = tid; i < 256; i += NTHR) if (lh[i]) atomicAdd(&hist2g[i], lh[i]);
  gbar(flags, release, 2);

  // ---- D: p24 + conservative select (whole p24 bucket) + contiguous gather ----
  if (tid < 64) {
    uint32_t b1, nd1, b2, nd2, b3, nd3;
    wave_bucket(hist0g, KPRE, &b1, &nd1);
    wave_bucket(hist16 + ((size_t)b1 << 8), nd1, &b2, &nd2);
    wave_bucket(hist2g, nd2, &b3, &nd3);
    if (tid == 0) { sp24 = (((b1 << 8) | b2) << 8) | b3; dcnt = 0; }
  }
  __syncthreads();
  {
    uint32_t p24 = sp24;
    uint32_t n = __hip_atomic_load(cntc + blk * CSTR, __ATOMIC_RELAXED, __HIP_MEMORY_SCOPE_AGENT);
    if (n > SEGC) n = SEGC;
    const unsigned long long* src = cand + (size_t)blk * SEGC;
    unsigned long long* dls = lk;  // LDS reuse
    for (uint32_t i = (uint32_t)tid; i < n; i += NTHR) {
      unsigned long long key = src[i];
      wave_compact((uint32_t)(key >> 40) <= p24, key, &dcnt, dls, (uint32_t)GCAP);
    }
    __syncthreads();
    if (tid == 0) {
      uint32_t c = dcnt; if (c > GCAP) c = GCAP;
      dbase = __hip_atomic_fetch_add(selcnt, c, __ATOMIC_RELAXED, __HIP_MEMORY_SCOPE_AGENT);
      dcnt = c;
    }
    __syncthreads();
    uint32_t c = dcnt, base = dbase;
    for (uint32_t i = (uint32_t)tid; i < c; i += NTHR) {
      unsigned long long key = dls[i];
      uint32_t pos = base + i;
      if (pos < (uint32_t)GCAP) {
        uint32_t idx = (uint32_t)key; if (idx >= NBOX) idx = 0;
        uint32_t u = (uint32_t)(key >> 32);
        x1a[pos] = boxes[idx];
        y1a[pos] = boxes[(size_t)NBOX + idx];
        x2a[pos] = boxes[(size_t)2 * NBOX + idx];
        y2a[pos] = boxes[(size_t)3 * NBOX + idx];
        vala[pos] = ord2f(~u);
        laba[pos] = (int)labs[idx];
        skg[pos] = key;
      }
    }
  }
  gbar(flags, release, 3);

  // ---- E: suppression pairs over dynamic triangular 64x64 tiles ----
  {
    uint32_t gc = __hip_atomic_load(selcnt, __ATOMIC_RELAXED, __HIP_MEMORY_SCOPE_AGENT);
    if (gc > (uint32_t)GCAP) gc = (uint32_t)GCAP;
    int rows = (int)((gc + 63) >> 6);
    int NT = rows * (rows + 1) / 2;
    float* psx1 = (float*)lk;  // staging carved from lk region (28 KB < 48 KB)
    float* psy1 = psx1 + NWAV * 64;
    float* psx2 = psy1 + NWAV * 64;
    float* psy2 = psx2 + NWAV * 64;
    float* psar = psy2 + NWAV * 64;
    unsigned long long* psk = (unsigned long long*)(psar + NWAV * 64);
    int W = blk * NWAV + wid;
    int wb = wid << 6;
    for (int T = W; T < NT; T += NBLK * NWAV) {
      float Rf = (float)rows;
      float disc = (2.0f * Rf + 1.0f) * (2.0f * Rf + 1.0f) - 8.0f * (float)T;
      disc = disc > 0.0f ? disc : 0.0f;
      int by = (int)(((2.0f * Rf + 1.0f) - sqrtf(disc)) * 0.5f);
      if (by < 0) by = 0;
      if (by > rows - 1) by = rows - 1;
      while (by > 0 && T < by * rows - (by * (by - 1)) / 2) --by;
      while (by < rows - 1 && T >= (by + 1) * rows - ((by + 1) * by) / 2) ++by;
      int cum = by * rows - (by * (by - 1)) / 2;
      int bx = by + (T - cum);
      int i = by * 64 + lane;
      int j0 = bx * 64 + lane;
      float cx1 = x1a[j0], cy1 = y1a[j0], cx2 = x2a[j0], cy2 = y2a[j0];
      psx1[wb + lane] = cx1; psy1[wb + lane] = cy1;
      psx2[wb + lane] = cx2; psy2[wb + lane] = cy2;
      psar[wb + lane] = fmaxf(cx2 - cx1, 0.0f) * fmaxf(cy2 - cy1, 0.0f);
      psk[wb + lane] = skg[j0];
      float x1i = x1a[i], y1i = y1a[i], x2i = x2a[i], y2i = y2a[i];
      unsigned long long rk = skg[i];
      float ari = fmaxf(x2i - x1i, 0.0f) * fmaxf(y2i - y1i, 0.0f);
      unsigned long long w = 0ull;
      #pragma unroll 8
      for (int jj = 0; jj < 64; ++jj) {
        int j = bx * 64 + jj;
        float iw = fmaxf(fminf(x2i, psx2[wb + jj]) - fmaxf(x1i, psx1[wb + jj]), 0.0f);
        float ih = fmaxf(fminf(y2i, psy2[wb + jj]) - fmaxf(y1i, psy1[wb + jj]), 0.0f);
        float inter = iw * ih;
        float den = ((ari + psar[wb + jj]) - inter) + 1e-8f;  // exact ref op order
        float iou = inter / den;
        if ((iou > 0.5f) && (j > i)) w |= (1ull << jj);
      }
      while (__ballot(w != 0ull)) {
        bool tk = (w != 0ull);
        uint32_t pr = 0;
        if (tk) {
          int b = __builtin_ctzll(w); w &= w - 1;
          int j = bx * 64 + b;
          bool i_sup = (rk < psk[wb + b]);  // smaller key suppresses
          pr = i_sup ? (((uint32_t)i << 16) | (uint32_t)j)
                     : (((uint32_t)j << 16) | (uint32_t)i);
        }
        wave_compact32(tk, pr, paircnt, pairs, (uint32_t)PCAP);
      }
    }
  }
  gbar(flags, release, 4);
  if (blk != 0) return;

  // ---- F (block 0): exact top-4096 cut + Jacobi fixpoint + top-500 emit ----
  uint32_t gc = __hip_atomic_load(selcnt, __ATOMIC_RELAXED, __HIP_MEMORY_SCOPE_AGENT);
  if (gc > (uint32_t)GCAP) gc = (uint32_t)GCAP;
  uint32_t np = __hip_atomic_load(paircnt, __ATOMIC_RELAXED, __HIP_MEMORY_SCOPE_AGENT);
  if (np > (uint32_t)PCAP) np = (uint32_t)PCAP;
  for (int t = tid; t < KPOST * 6; t += NTHR) out[t] = 0.0f;
  if (tid < 512) kkbuf[tid] = ~0ull;
  for (int t = tid; t < GCAP; t += NTHR) lk[t] = (t < (int)gc) ? skg[t] : ~0ull;
  if (tid == 0) { orlo = 0; orhi = 0; andlo = ~0u; andhi = ~0u; scnt2 = 0; }
  __syncthreads();

  // radix #1: T1 = exact need1-th smallest key among gathered
  uint32_t need1 = (gc < (uint32_t)KPRE) ? gc : (uint32_t)KPRE;
  if (need1 == 0) return;
  {
    unsigned long long myor = 0ull, myand = ~0ull;
    for (int t = tid; t < (int)gc; t += NTHR) {
      unsigned long long k = lk[t];
      myor |= k; myand &= k;
    }
    #pragma unroll
    for (int d = 1; d < 64; d <<= 1) { myor |= shflx64(myor, d); myand &= shflx64(myand, d); }
    if (lane == 0) {
      atomicOr(&orlo, (uint32_t)myor); atomicOr(&orhi, (uint32_t)(myor >> 32));
      atomicAnd(&andlo, (uint32_t)myand); atomicAnd(&andhi, (uint32_t)(myand >> 32));
    }
  }
  __syncthreads();
  unsigned long long T1;
  {
    unsigned long long vor = ((unsigned long long)orhi << 32) | orlo;
    unsigned long long vand = ((unsigned long long)andhi << 32) | andlo;
    unsigned long long diff = vor ^ vand;
    unsigned long long pre = 0;
    uint32_t need = need1;
    for (int b = 7; b >= 0; --b) {
      uint32_t db = (uint32_t)(diff >> (8 * b)) & 255u;
      if (db == 0) { pre = (pre << 8) | ((uint32_t)(vand >> (8 * b)) & 255u); continue; }
      if (tid < 256) hsel[tid] = 0;
      __syncthreads();
      for (int t = tid; t < (int)gc; t += NTHR) {
        unsigned long long k = lk[t];
        bool pm = (b == 7) ? true : ((k >> (8 * b + 8)) == pre);
        if (pm) atomicAdd(&hsel[(uint32_t)(k >> (8 * b)) & 255u], 1u);
      }
      __syncthreads();
      if (tid < 64) {
        uint32_t c0 = hsel[4 * tid], c1 = hsel[4 * tid + 1],
                 c2 = hsel[4 * tid + 2], c3 = hsel[4 * tid + 3];
        uint32_t s = c0 + c1 + c2 + c3;
        uint32_t p = s;
        #pragma unroll
        for (int d = 1; d < 64; d <<= 1) {
          uint32_t v = __shfl_up(p, d, 64);
          if (tid >= d) p += v;
        }
        uint32_t e0 = p - s, e1 = e0 + c0, e2 = e1 + c1, e3 = e2 + c2, e4 = e3 + c3;
        uint32_t eb[5] = {e0, e1, e2, e3, e4};
        #pragma unroll
        for (int q = 0; q < 4; ++q)
          if (eb[q] < need && need <= eb[q + 1]) {
            spre = (pre << 8) | (uint32_t)(4 * tid + q);
            sneedS = need - eb[q];
          }
      }
      __syncthreads();
      pre = spre; need = sneedS;
      __syncthreads();
    }
    T1 = pre;
  }

  // validity: exact top-4096 member AND score >= 0.1
  for (int t = tid; t < GCAP; t += NTHR) {
    unsigned long long k = lk[t];
    float v = ord2f(~(uint32_t)(k >> 32));
    bool ok = (k <= T1) && (v >= 0.1f);
    unsigned long long bm = __ballot(ok);
    if (lane == 0) { validm[t >> 6] = bm; accm[t >> 6] = bm; }
  }
  __syncthreads();

  // Jacobi fixpoint of A[i] = V[i] & forall (j->i): !A[j]  (== greedy NMS)
  while (true) {
    __syncthreads();
    if (tid < NMW * 2) supp[tid] = 0;
    if (tid == 0) chg = 0;
    __syncthreads();
    for (uint32_t p = (uint32_t)tid; p < np; p += NTHR) {
      uint32_t pr = pairs[p];
      uint32_t i = pr >> 16, j = pr & 0xffffu;
      if ((accm[i >> 6] >> (i & 63)) & 1ull) atomicOr(&supp[j >> 5], 1u << (j & 31));
    }
    __syncthreads();
    if (tid < NMW) {
      unsigned long long s = ((unsigned long long)supp[2 * tid + 1] << 32) | supp[2 * tid];
      unsigned long long na = validm[tid] & ~s;
      if (na != accm[tid]) { accm[tid] = na; atomicOr(&chg, 1u); }
    }
    __syncthreads();
    if (chg == 0) break;
  }

  // ---- top-KPOST of survivors (radix narrowing) + rank emit ----
  if (tid == 0) {
    uint32_t ns = 0;
    for (int l = 0; l < NMW; ++l) ns += (uint32_t)__builtin_popcountll(accm[l]);
    sneedS = (ns < (uint32_t)KPOST) ? ns : (uint32_t)KPOST;
    orlo = 0; orhi = 0; andlo = ~0u; andhi = ~0u;
  }
  __syncthreads();
  uint32_t need0 = sneedS;
  if (need0 == 0) return;
  {
    unsigned long long myor = 0ull, myand = ~0ull;
    for (int t = tid; t < GCAP; t += NTHR) {
      if ((accm[t >> 6] >> (t & 63)) & 1ull) {
        unsigned long long k = lk[t];
        myor |= k; myand &= k;
      }
    }
    #pragma unroll
    for (int d = 1; d < 64; d <<= 1) { myor |= shflx64(myor, d); myand &= shflx64(myand, d); }
    if (lane == 0) {
      atomicOr(&orlo, (uint32_t)myor); atomicOr(&orhi, (uint32_t)(myor >> 32));
      atomicAnd(&andlo, (uint32_t)myand); atomicAnd(&andhi, (uint32_t)(myand >> 32));
    }
  }
  __syncthreads();
  unsigned long long T2;
  {
    unsigned long long vor = ((unsigned long long)orhi << 32) | orlo;
    unsigned long long vand = ((unsigned long long)andhi << 32) | andlo;
    unsigned long long diff = vor ^ vand;
    unsigned long long pre = 0;
    uint32_t need = need0;
    for (int b = 7; b >= 0; --b) {
      uint32_t db = (uint32_t)(diff >> (8 * b)) & 255u;
      if (db == 0) { pre = (pre << 8) | ((uint32_t)(vand >> (8 * b)) & 255u); continue; }
      if (tid < 256) hsel[tid] = 0;
      __syncthreads();
      for (int t = tid; t < GCAP; t += NTHR) {
        if ((accm[t >> 6] >> (t & 63)) & 1ull) {
          unsigned long long k = lk[t];
          bool pm = (b == 7) ? true : ((k >> (8 * b + 8)) == pre);
          if (pm) atomicAdd(&hsel[(uint32_t)(k >> (8 * b)) & 255u], 1u);
        }
      }
      __syncthreads();
      if (tid < 64) {
        uint32_t c0 = hsel[4 * tid], c1 = hsel[4 * tid + 1],
                 c2 = hsel[4 * tid + 2], c3 = hsel[4 * tid + 3];
        uint32_t s = c0 + c1 + c2 + c3;
        uint32_t p = s;
        #pragma unroll
        for (int d = 1; d < 64; d <<= 1) {
          uint32_t v = __shfl_up(p, d, 64);
          if (tid >= d) p += v;
        }
        uint32_t e0 = p - s, e1 = e0 + c0, e2 = e1 + c1, e3 = e2 + c2, e4 = e3 + c3;
        uint32_t eb[5] = {e0, e1, e2, e3, e4};
        #pragma unroll
        for (int q = 0; q < 4; ++q)
          if (eb[q] < need && need <= eb[q + 1]) {
            spre = (pre << 8) | (uint32_t)(4 * tid + q);
            sneedS = need - eb[q];
          }
      }
      __syncthreads();
      pre = spre; need = sneedS;
      __syncthreads();
    }
    T2 = pre;
  }

  for (int t = tid; t < GCAP; t += NTHR) {
    bool take = ((accm[t >> 6] >> (t & 63)) & 1ull) && (lk[t] <= T2);
    wave_compact32(take, (uint32_t)t, &scnt2, lsel, 512u);
  }
  __syncthreads();
  uint32_t cnt = min(scnt2, 512u);
  if (tid < (int)cnt) kkbuf[tid] = lk[lsel[tid]];
  __syncthreads();
  if (tid < (int)cnt) {
    unsigned long long k0 = kkbuf[tid];
    uint32_t rank = 0;
    #pragma unroll 8
    for (uint32_t p = 0; p < 512u; ++p) rank += (kkbuf[p] < k0) ? 1u : 0u;
    if (rank < (uint32_t)KPOST) {
      int i = (int)lsel[tid];
      out[rank * 6 + 0] = x1a[i];
      out[rank * 6 + 1] = y1a[i];
      out[rank * 6 + 2] = x2a[i];
      out[rank * 6 + 3] = y2a[i];
      out[rank * 6 + 4] = vala[i];
      out[rank * 6 + 5] = (float)laba[i];
    }
  }
}

extern "C" void kernel_launch(void* const* d_in, const int* in_sizes, int n_in,
                              void* d_out, int out_size, void* d_ws, size_t ws_size,
                              hipStream_t stream) {
  const float* boxes = (const float*)d_in[0];
  const float* cls   = (const float*)d_in[1];
  float* out = (float*)d_out;
  char* ws = (char*)d_ws;

  uint32_t* keys = (uint32_t*)(ws + OFF_KEYS);
  unsigned long long* cand = (unsigned long long*)(ws + OFF_CAND);
  uint32_t* pairs = (uint32_t*)(ws + OFF_PAIRS);
  float* x1a = (float*)(ws + OFF_ARR);
  float* y1a = x1a + GCAP;
  float* x2a = y1a + GCAP;
  float* y2a = x2a + GCAP;
  float* vala = y2a + GCAP;
  int* laba = (int*)(vala + GCAP);
  unsigned long long* skg = (unsigned long long*)(laba + GCAP);
  uint8_t* labs = (uint8_t*)(ws + OFF_LAB);
  uint32_t* zbase = (uint32_t*)(ws + OFF_ZERO);
  uint32_t* hist0 = zbase + ZW_HIST0;
  uint32_t* hist2 = zbase + ZW_HIST2;
  uint32_t* hist16 = zbase + ZW_HIST16;
  uint32_t* cntc = zbase + ZW_CNTC;
  uint32_t* state = zbase + ZW_STATE;

  hipMemsetAsync(ws + OFF_ZERO, 0, ZERO_BYTES, stream);
  // Normal (graph-capturable) launch: 512 blocks, 2/CU guaranteed by LDS(~59KB)+VGPR(<=64).
  k_all<<<dim3(NBLK), dim3(NTHR), 0, stream>>>(
      boxes, cls, keys, labs, cand, cntc, hist0, hist2, hist16, state,
      x1a, y1a, x2a, y2a, vala, laba, skg, pairs, out);
}

// Round 7
// 267.438 us; speedup vs baseline: 19.0556x; 19.0556x over previous
//
#include <hip/hip_runtime.h>
#include <stdint.h>

#define NBOX 2000000
#define NCLS 10
#define KPRE 4096
#define KPOST 500
#define GCAP 6144        // gathered candidate cap (>= 4096 + p24 boundary bucket)
#define NMW  (GCAP / 64) // 96 mask words
#define PCAP 131072      // pair cap
#define LPC  16384       // LDS pair cache in k_fix (64 KB)
#define PROWS (GCAP / 64) // 96 tile rows

// ---- workspace layout (bytes) ----
#define OFF_KEYS  ((size_t)0)                          // NBOX*4 = 8,000,000
#define OFF_PAIRS ((size_t)8000000)                    // PCAP*4
#define OFF_ARR   (OFF_PAIRS + (size_t)PCAP * 4)       // 32 B * GCAP
#define OFF_LAB   (OFF_ARR + (size_t)GCAP * 32)        // NBOX u8
#define OFF_ZERO  (OFF_LAB + (size_t)NBOX)
// zero region (words): hist0[256] | hist2[256] | hist16[65536] | state[16]
#define ZW_HIST0  0
#define ZW_HIST2  256
#define ZW_HIST16 512
#define ZW_STATE  (512 + 65536)
#define ZERO_WORDS (ZW_STATE + 16)
#define ZERO_BYTES ((size_t)ZERO_WORDS * 4)

// ord-space constant: scores in [0.5,1) have (u>>16) in [0x4080, 0x40FF] (128 hot bins)
#define HOTBASE 0x4080u

__device__ __forceinline__ uint32_t f2ord(float f) {
  uint32_t b = __float_as_uint(f);
  return (b & 0x80000000u) ? ~b : (b | 0x80000000u);
}
__device__ __forceinline__ float ord2f(uint32_t ord) {
  uint32_t b = (ord & 0x80000000u) ? (ord ^ 0x80000000u) : ~ord;
  return __uint_as_float(b);
}

__device__ __forceinline__ unsigned long long shflx64(unsigned long long v, int mask) {
  union { unsigned long long u; int i[2]; } a; a.u = v;
  a.i[0] = __shfl_xor(a.i[0], mask, 64);
  a.i[1] = __shfl_xor(a.i[1], mask, 64);
  return a.u;
}

// full-wave (lanes 0..63): bucket of the need-th smallest in h[256] (global or LDS)
__device__ __forceinline__ void wave_bucket(const uint32_t* __restrict__ h, uint32_t need,
                                            uint32_t* bin_out, uint32_t* nd_out) {
  int l = threadIdx.x & 63;
  uint4 h4 = reinterpret_cast<const uint4*>(h)[l];
  uint32_t s = h4.x + h4.y + h4.z + h4.w;
  uint32_t p = s;
  #pragma unroll
  for (int d = 1; d < 64; d <<= 1) {
    uint32_t v = __shfl_up(p, d, 64);
    if (l >= d) p += v;
  }
  uint32_t e0 = p - s, e1 = e0 + h4.x, e2 = e1 + h4.y, e3 = e2 + h4.z, e4 = e3 + h4.w;
  uint32_t eb[5] = {e0, e1, e2, e3, e4};
  uint32_t bin = 0xFFFFFFFFu, nd = 1;
  #pragma unroll
  for (int q = 0; q < 4; ++q)
    if (eb[q] < need && need <= eb[q + 1]) { bin = (uint32_t)(4 * l + q); nd = need - eb[q]; }
  unsigned long long mm = __ballot(bin != 0xFFFFFFFFu);
  int src = mm ? __builtin_ctzll(mm) : 0;
  *bin_out = (uint32_t)__shfl((int)bin, src);
  *nd_out  = (uint32_t)__shfl((int)nd, src);
}

__device__ __forceinline__ void wave_compact32(bool take, uint32_t key,
                                               uint32_t* counter, uint32_t* buf,
                                               uint32_t cap) {
  unsigned long long mm = __ballot(take);
  if (take) {
    int lane = threadIdx.x & 63;
    unsigned long long lt = (lane == 0) ? 0ull : (~0ull >> (64 - lane));
    int rank = __builtin_popcountll(mm & lt);
    int leader = __builtin_ctzll(mm);
    uint32_t base = 0;
    if (rank == 0) base = atomicAdd(counter, (uint32_t)__builtin_popcountll(mm));
    base = __shfl(base, leader);
    uint32_t pos = base + (uint32_t)rank;
    if (pos < cap) buf[pos] = key;
  }
}

// tree max-of-10 with first-max index (strict > merges == sequential argmax)
__device__ __forceinline__ void tree10(float v0, float v1, float v2, float v3, float v4,
                                       float v5, float v6, float v7, float v8, float v9,
                                       float* mv, int* mi) {
  float b0, b1, b2, b3, b4; int j0, j1, j2, j3, j4;
  if (v1 > v0) { b0 = v1; j0 = 1; } else { b0 = v0; j0 = 0; }
  if (v3 > v2) { b1 = v3; j1 = 3; } else { b1 = v2; j1 = 2; }
  if (v5 > v4) { b2 = v5; j2 = 5; } else { b2 = v4; j2 = 4; }
  if (v7 > v6) { b3 = v7; j3 = 7; } else { b3 = v6; j3 = 6; }
  if (v9 > v8) { b4 = v9; j4 = 9; } else { b4 = v8; j4 = 8; }
  if (b1 > b0) { b0 = b1; j0 = j1; }
  if (b3 > b2) { b2 = b3; j2 = j3; }
  if (b2 > b0) { b0 = b2; j0 = j2; }
  if (b4 > b0) { b0 = b4; j0 = j4; }
  *mv = b0; *mi = j0;
}

// ---------------- kernels ----------------

// 1) score pass: cls (80 MB) -> ord keys + labels; hist0 (byte0) + hist16 (16-bit prefix).
//    Hot prefix range [0x4080,0x4100) handled in LDS; rare bins via global atomics.
__global__ void k_score(const float* __restrict__ cls, uint32_t* __restrict__ keys,
                        uint8_t* __restrict__ labs, uint32_t* __restrict__ hist0,
                        uint32_t* __restrict__ hist16) {
  __shared__ uint32_t lh0[256];
  __shared__ uint32_t lhr[128];
  for (int i = threadIdx.x; i < 256; i += blockDim.x) lh0[i] = 0;
  for (int i = threadIdx.x; i < 128; i += blockDim.x) lhr[i] = 0;
  __syncthreads();
  const int nvec = NBOX / 4;
  const float4* cp = reinterpret_cast<const float4*>(cls);
  const int pstr = NBOX / 4;
  for (int v = blockIdx.x * blockDim.x + threadIdx.x; v < nvec; v += gridDim.x * blockDim.x) {
    float4 x0 = cp[v];
    float4 x1 = cp[pstr * 1 + v];
    float4 x2 = cp[pstr * 2 + v];
    float4 x3 = cp[pstr * 3 + v];
    float4 x4 = cp[pstr * 4 + v];
    float4 x5 = cp[pstr * 5 + v];
    float4 x6 = cp[pstr * 6 + v];
    float4 x7 = cp[pstr * 7 + v];
    float4 x8 = cp[pstr * 8 + v];
    float4 x9 = cp[pstr * 9 + v];
    uint32_t u4[4]; int l4[4];
    float mv; int mi;
    tree10(x0.x, x1.x, x2.x, x3.x, x4.x, x5.x, x6.x, x7.x, x8.x, x9.x, &mv, &mi);
    { float ms = (mv >= 0.1f) ? mv : -1.0f; u4[0] = ~f2ord(ms); l4[0] = mi; }
    tree10(x0.y, x1.y, x2.y, x3.y, x4.y, x5.y, x6.y, x7.y, x8.y, x9.y, &mv, &mi);
    { float ms = (mv >= 0.1f) ? mv : -1.0f; u4[1] = ~f2ord(ms); l4[1] = mi; }
    tree10(x0.z, x1.z, x2.z, x3.z, x4.z, x5.z, x6.z, x7.z, x8.z, x9.z, &mv, &mi);
    { float ms = (mv >= 0.1f) ? mv : -1.0f; u4[2] = ~f2ord(ms); l4[2] = mi; }
    tree10(x0.w, x1.w, x2.w, x3.w, x4.w, x5.w, x6.w, x7.w, x8.w, x9.w, &mv, &mi);
    { float ms = (mv >= 0.1f) ? mv : -1.0f; u4[3] = ~f2ord(ms); l4[3] = mi; }
    #pragma unroll
    for (int q = 0; q < 4; ++q) {
      uint32_t b16 = u4[q] >> 16;
      uint32_t rel = b16 - HOTBASE;
      if (rel < 128u) atomicAdd(&lhr[rel], 1u);
      else { atomicAdd(&hist16[b16], 1u); atomicAdd(&lh0[b16 >> 8], 1u); }
    }
    reinterpret_cast<uint4*>(keys)[v] = make_uint4(u4[0], u4[1], u4[2], u4[3]);
    uchar4 lb; lb.x = (uint8_t)l4[0]; lb.y = (uint8_t)l4[1];
    lb.z = (uint8_t)l4[2]; lb.w = (uint8_t)l4[3];
    reinterpret_cast<uchar4*>(labs)[v] = lb;
  }
  __syncthreads();
  for (int i = threadIdx.x; i < 128; i += blockDim.x) {
    uint32_t c = lhr[i];
    if (c) { atomicAdd(&hist16[HOTBASE + i], c); atomicAdd(&lh0[HOTBASE >> 8], c); }
  }
  __syncthreads();
  for (int i = threadIdx.x; i < 256; i += blockDim.x)
    if (lh0[i]) atomicAdd(&hist0[i], lh0[i]);
}

// 2) keys pass: byte2 histogram among prefix == p16 (p16 computed inline, exact);
//    also sentinel-inits the gather arrays.
__global__ void k_hist2(const uint32_t* __restrict__ keys,
                        const uint32_t* __restrict__ hist0,
                        const uint32_t* __restrict__ hist16,
                        uint32_t* __restrict__ hist2,
                        float* __restrict__ x1a, float* __restrict__ y1a,
                        float* __restrict__ x2a, float* __restrict__ y2a,
                        float* __restrict__ vala, int* __restrict__ laba,
                        unsigned long long* __restrict__ skg) {
  __shared__ uint32_t lh[256];
  __shared__ uint32_t sp16;
  if (threadIdx.x < 64) {
    uint32_t b1, nd1, b2, nd2;
    wave_bucket(hist0, KPRE, &b1, &nd1);
    wave_bucket(hist16 + ((size_t)b1 << 8), nd1, &b2, &nd2);
    if (threadIdx.x == 0) sp16 = (b1 << 8) | b2;
  }
  for (int i = threadIdx.x; i < 256; i += blockDim.x) lh[i] = 0;
  __syncthreads();
  uint32_t p16 = sp16;
  const int nvec = NBOX / 4;
  int gtid = blockIdx.x * blockDim.x + threadIdx.x;
  int gtot = gridDim.x * blockDim.x;
  for (int v = gtid; v < nvec; v += gtot) {
    uint4 kv = reinterpret_cast<const uint4*>(keys)[v];
    if ((kv.x >> 16) == p16) atomicAdd(&lh[(kv.x >> 8) & 255u], 1u);
    if ((kv.y >> 16) == p16) atomicAdd(&lh[(kv.y >> 8) & 255u], 1u);
    if ((kv.z >> 16) == p16) atomicAdd(&lh[(kv.z >> 8) & 255u], 1u);
    if ((kv.w >> 16) == p16) atomicAdd(&lh[(kv.w >> 8) & 255u], 1u);
  }
  for (int t = gtid; t < GCAP; t += gtot) {
    x1a[t] = 0.0f; y1a[t] = 0.0f; x2a[t] = 0.0f; y2a[t] = 0.0f;
    vala[t] = -1.0f; laba[t] = 0; skg[t] = ~0ull;
  }
  __syncthreads();
  for (int i = threadIdx.x; i < 256; i += blockDim.x)
    if (lh[i]) atomicAdd(&hist2[i], lh[i]);
}

// 3) keys pass: select (u>>8) <= p24 (<= GCAP entries, superset of exact top-4096),
//    gather boxes/labels/values directly into final slots via one global counter.
__global__ void k_selgather(const uint32_t* __restrict__ keys,
                            const float* __restrict__ boxes, const uint8_t* __restrict__ labs,
                            const uint32_t* __restrict__ hist0,
                            const uint32_t* __restrict__ hist16,
                            const uint32_t* __restrict__ hist2,
                            uint32_t* __restrict__ selcnt,
                            float* __restrict__ x1a, float* __restrict__ y1a,
                            float* __restrict__ x2a, float* __restrict__ y2a,
                            float* __restrict__ vala, int* __restrict__ laba,
                            unsigned long long* __restrict__ skg) {
  __shared__ uint32_t sp24;
  if (threadIdx.x < 64) {
    uint32_t b1, nd1, b2, nd2, b3, nd3;
    wave_bucket(hist0, KPRE, &b1, &nd1);
    wave_bucket(hist16 + ((size_t)b1 << 8), nd1, &b2, &nd2);
    wave_bucket(hist2, nd2, &b3, &nd3);
    if (threadIdx.x == 0) sp24 = (((b1 << 8) | b2) << 8) | b3;
  }
  __syncthreads();
  uint32_t p24 = sp24;
  const int nvec = NBOX / 4;
  int lane = threadIdx.x & 63;
  for (int v = blockIdx.x * blockDim.x + threadIdx.x; v < nvec; v += gridDim.x * blockDim.x) {
    uint4 kv = reinterpret_cast<const uint4*>(keys)[v];
    uint32_t us[4] = {kv.x, kv.y, kv.z, kv.w};
    #pragma unroll
    for (int q = 0; q < 4; ++q) {
      uint32_t u = us[q];
      bool take = ((u >> 8) <= p24);
      unsigned long long mm = __ballot(take);
      if (take) {
        unsigned long long lt = (lane == 0) ? 0ull : (~0ull >> (64 - lane));
        int rank = __builtin_popcountll(mm & lt);
        int leader = __builtin_ctzll(mm);
        uint32_t base = 0;
        if (rank == 0) base = atomicAdd(selcnt, (uint32_t)__builtin_popcountll(mm));
        base = __shfl(base, leader);
        uint32_t pos = base + (uint32_t)rank;
        if (pos < (uint32_t)GCAP) {
          uint32_t idx = (uint32_t)(4 * v + q);
          x1a[pos] = boxes[idx];
          y1a[pos] = boxes[(size_t)NBOX + idx];
          x2a[pos] = boxes[(size_t)2 * NBOX + idx];
          y2a[pos] = boxes[(size_t)3 * NBOX + idx];
          vala[pos] = ord2f(~u);
          laba[pos] = (int)labs[idx];
          skg[pos] = ((unsigned long long)u << 32) | idx;
        }
      }
    }
  }
}

// 4) suppression pairs: 96x96 triangular 64x64 tiles; sentinel boxes produce no pairs.
__global__ void k_pairs(const float* __restrict__ x1a, const float* __restrict__ y1a,
                        const float* __restrict__ x2a, const float* __restrict__ y2a,
                        const unsigned long long* __restrict__ skg,
                        uint32_t* __restrict__ paircnt, uint32_t* __restrict__ pairs) {
#pragma clang fp contract(off)
  int bx = blockIdx.x, by = blockIdx.y;
  if (bx < by) return;
  int t = threadIdx.x;  // 64 threads
  int i = by * 64 + t;
  __shared__ float sx1[64], sy1[64], sx2[64], sy2[64], sar[64];
  __shared__ unsigned long long sk[64];
  int j0 = bx * 64 + t;
  float cx1 = x1a[j0], cy1 = y1a[j0], cx2 = x2a[j0], cy2 = y2a[j0];
  sx1[t] = cx1; sy1[t] = cy1; sx2[t] = cx2; sy2[t] = cy2;
  sar[t] = fmaxf(cx2 - cx1, 0.0f) * fmaxf(cy2 - cy1, 0.0f);
  sk[t] = skg[j0];
  __syncthreads();
  float x1i = x1a[i], y1i = y1a[i], x2i = x2a[i], y2i = y2a[i];
  unsigned long long rk = skg[i];
  float ari = fmaxf(x2i - x1i, 0.0f) * fmaxf(y2i - y1i, 0.0f);
  unsigned long long w = 0ull;
  #pragma unroll 8
  for (int jj = 0; jj < 64; ++jj) {
    int j = bx * 64 + jj;
    float iw = fmaxf(fminf(x2i, sx2[jj]) - fmaxf(x1i, sx1[jj]), 0.0f);
    float ih = fmaxf(fminf(y2i, sy2[jj]) - fmaxf(y1i, sy1[jj]), 0.0f);
    float inter = iw * ih;
    float den = ((ari + sar[jj]) - inter) + 1e-8f;  // exact ref op order
    float iou = inter / den;
    if ((iou > 0.5f) && (j > i)) w |= (1ull << jj);
  }
  while (__ballot(w != 0ull)) {
    bool tk = (w != 0ull);
    uint32_t pr = 0;
    if (tk) {
      int b = __builtin_ctzll(w); w &= w - 1;
      int j = bx * 64 + b;
      bool i_sup = (rk < sk[b]);  // smaller key (higher score / lower orig idx) suppresses
      pr = i_sup ? (((uint32_t)i << 16) | (uint32_t)j)
                 : (((uint32_t)j << 16) | (uint32_t)i);
    }
    wave_compact32(tk, pr, paircnt, pairs, (uint32_t)PCAP);
  }
}

// 5) single block: exact top-4096 cut (radix) + Jacobi fixpoint + top-500 emit.
__global__ void __launch_bounds__(1024) k_fix(
    const uint32_t* __restrict__ state, const uint32_t* __restrict__ pairs,
    const float* __restrict__ x1a, const float* __restrict__ y1a,
    const float* __restrict__ x2a, const float* __restrict__ y2a,
    const float* __restrict__ vala, const int* __restrict__ laba,
    const unsigned long long* __restrict__ skg, float* __restrict__ out) {
  __shared__ unsigned long long lk[GCAP];
  __shared__ uint32_t lpair[LPC];
  __shared__ unsigned long long validm[NMW], accm[NMW];
  __shared__ uint32_t supp[NMW * 2];
  __shared__ uint32_t hsel[256];
  __shared__ uint32_t lsel[512];
  __shared__ unsigned long long kkbuf[512];
  __shared__ uint32_t chg, scnt2, sneedS;
  __shared__ unsigned long long spre;
  __shared__ uint32_t orlo, orhi, andlo, andhi;
  int tid = threadIdx.x;
  int lane = tid & 63;

  uint32_t gc = state[0]; if (gc > (uint32_t)GCAP) gc = (uint32_t)GCAP;
  uint32_t np = state[1]; if (np > (uint32_t)PCAP) np = (uint32_t)PCAP;
  for (int t = tid; t < KPOST * 6; t += 1024) out[t] = 0.0f;
  if (tid < 512) kkbuf[tid] = ~0ull;
  for (int t = tid; t < GCAP; t += 1024) lk[t] = (t < (int)gc) ? skg[t] : ~0ull;
  bool plds = (np <= (uint32_t)LPC);
  if (plds) for (uint32_t p = (uint32_t)tid; p < np; p += 1024) lpair[p] = pairs[p];
  if (tid == 0) { orlo = 0; orhi = 0; andlo = ~0u; andhi = ~0u; scnt2 = 0; }
  __syncthreads();

  // radix #1: T1 = exact need1-th smallest key among gathered
  uint32_t need1 = (gc < (uint32_t)KPRE) ? gc : (uint32_t)KPRE;
  if (need1 == 0) return;
  {
    unsigned long long myor = 0ull, myand = ~0ull;
    for (int t = tid; t < (int)gc; t += 1024) {
      unsigned long long k = lk[t];
      myor |= k; myand &= k;
    }
    #pragma unroll
    for (int d = 1; d < 64; d <<= 1) { myor |= shflx64(myor, d); myand &= shflx64(myand, d); }
    if (lane == 0) {
      atomicOr(&orlo, (uint32_t)myor); atomicOr(&orhi, (uint32_t)(myor >> 32));
      atomicAnd(&andlo, (uint32_t)myand); atomicAnd(&andhi, (uint32_t)(myand >> 32));
    }
  }
  __syncthreads();
  unsigned long long T1;
  {
    unsigned long long vor = ((unsigned long long)orhi << 32) | orlo;
    unsigned long long vand = ((unsigned long long)andhi << 32) | andlo;
    unsigned long long diff = vor ^ vand;
    unsigned long long pre = 0;
    uint32_t need = need1;
    for (int b = 7; b >= 0; --b) {
      uint32_t db = (uint32_t)(diff >> (8 * b)) & 255u;
      if (db == 0) { pre = (pre << 8) | ((uint32_t)(vand >> (8 * b)) & 255u); continue; }
      if (tid < 256) hsel[tid] = 0;
      __syncthreads();
      for (int t = tid; t < (int)gc; t += 1024) {
        unsigned long long k = lk[t];
        bool pm = (b == 7) ? true : ((k >> (8 * b + 8)) == pre);
        if (pm) atomicAdd(&hsel[(uint32_t)(k >> (8 * b)) & 255u], 1u);
      }
      __syncthreads();
      if (tid < 64) {
        uint32_t c0 = hsel[4 * tid], c1 = hsel[4 * tid + 1],
                 c2 = hsel[4 * tid + 2], c3 = hsel[4 * tid + 3];
        uint32_t s = c0 + c1 + c2 + c3;
        uint32_t p = s;
        #pragma unroll
        for (int d = 1; d < 64; d <<= 1) {
          uint32_t v = __shfl_up(p, d, 64);
          if (tid >= d) p += v;
        }
        uint32_t e0 = p - s, e1 = e0 + c0, e2 = e1 + c1, e3 = e2 + c2, e4 = e3 + c3;
        uint32_t eb[5] = {e0, e1, e2, e3, e4};
        #pragma unroll
        for (int q = 0; q < 4; ++q)
          if (eb[q] < need && need <= eb[q + 1]) {
            spre = (pre << 8) | (uint32_t)(4 * tid + q);
            sneedS = need - eb[q];
          }
      }
      __syncthreads();
      pre = spre; need = sneedS;
      __syncthreads();
    }
    T1 = pre;
  }

  // validity: exact top-4096 member AND score >= 0.1
  for (int t = tid; t < GCAP; t += 1024) {
    unsigned long long k = lk[t];
    float v = ord2f(~(uint32_t)(k >> 32));
    bool ok = (k <= T1) && (v >= 0.1f);
    unsigned long long bm = __ballot(ok);
    if (lane == 0) { validm[t >> 6] = bm; accm[t >> 6] = bm; }
  }
  __syncthreads();

  // Jacobi fixpoint of A[i] = V[i] & forall (j->i): !A[j]  (== greedy NMS)
  while (true) {
    __syncthreads();
    if (tid < NMW * 2) supp[tid] = 0;
    if (tid == 0) chg = 0;
    __syncthreads();
    if (plds) {
      for (uint32_t p = (uint32_t)tid; p < np; p += 1024) {
        uint32_t pr = lpair[p];
        uint32_t i = pr >> 16, j = pr & 0xffffu;
        if ((accm[i >> 6] >> (i & 63)) & 1ull) atomicOr(&supp[j >> 5], 1u << (j & 31));
      }
    } else {
      for (uint32_t p = (uint32_t)tid; p < np; p += 1024) {
        uint32_t pr = pairs[p];
        uint32_t i = pr >> 16, j = pr & 0xffffu;
        if ((accm[i >> 6] >> (i & 63)) & 1ull) atomicOr(&supp[j >> 5], 1u << (j & 31));
      }
    }
    __syncthreads();
    if (tid < NMW) {
      unsigned long long s = ((unsigned long long)supp[2 * tid + 1] << 32) | supp[2 * tid];
      unsigned long long na = validm[tid] & ~s;
      if (na != accm[tid]) { accm[tid] = na; atomicOr(&chg, 1u); }
    }
    __syncthreads();
    if (chg == 0) break;
  }

  // ---- top-KPOST of survivors (radix narrowing) + rank emit ----
  if (tid == 0) {
    uint32_t ns = 0;
    for (int l = 0; l < NMW; ++l) ns += (uint32_t)__builtin_popcountll(accm[l]);
    sneedS = (ns < (uint32_t)KPOST) ? ns : (uint32_t)KPOST;
    orlo = 0; orhi = 0; andlo = ~0u; andhi = ~0u;
  }
  __syncthreads();
  uint32_t need0 = sneedS;
  if (need0 == 0) return;
  {
    unsigned long long myor = 0ull, myand = ~0ull;
    for (int t = tid; t < GCAP; t += 1024) {
      if ((accm[t >> 6] >> (t & 63)) & 1ull) {
        unsigned long long k = lk[t];
        myor |= k; myand &= k;
      }
    }
    #pragma unroll
    for (int d = 1; d < 64; d <<= 1) { myor |= shflx64(myor, d); myand &= shflx64(myand, d); }
    if (lane == 0) {
      atomicOr(&orlo, (uint32_t)myor); atomicOr(&orhi, (uint32_t)(myor >> 32));
      atomicAnd(&andlo, (uint32_t)myand); atomicAnd(&andhi, (uint32_t)(myand >> 32));
    }
  }
  __syncthreads();
  unsigned long long T2;
  {
    unsigned long long vor = ((unsigned long long)orhi << 32) | orlo;
    unsigned long long vand = ((unsigned long long)andhi << 32) | andlo;
    unsigned long long diff = vor ^ vand;
    unsigned long long pre = 0;
    uint32_t need = need0;
    for (int b = 7; b >= 0; --b) {
      uint32_t db = (uint32_t)(diff >> (8 * b)) & 255u;
      if (db == 0) { pre = (pre << 8) | ((uint32_t)(vand >> (8 * b)) & 255u); continue; }
      if (tid < 256) hsel[tid] = 0;
      __syncthreads();
      for (int t = tid; t < GCAP; t += 1024) {
        if ((accm[t >> 6] >> (t & 63)) & 1ull) {
          unsigned long long k = lk[t];
          bool pm = (b == 7) ? true : ((k >> (8 * b + 8)) == pre);
          if (pm) atomicAdd(&hsel[(uint32_t)(k >> (8 * b)) & 255u], 1u);
        }
      }
      __syncthreads();
      if (tid < 64) {
        uint32_t c0 = hsel[4 * tid], c1 = hsel[4 * tid + 1],
                 c2 = hsel[4 * tid + 2], c3 = hsel[4 * tid + 3];
        uint32_t s = c0 + c1 + c2 + c3;
        uint32_t p = s;
        #pragma unroll
        for (int d = 1; d < 64; d <<= 1) {
          uint32_t v = __shfl_up(p, d, 64);
          if (tid >= d) p += v;
        }
        uint32_t e0 = p - s, e1 = e0 + c0, e2 = e1 + c1, e3 = e2 + c2, e4 = e3 + c3;
        uint32_t eb[5] = {e0, e1, e2, e3, e4};
        #pragma unroll
        for (int q = 0; q < 4; ++q)
          if (eb[q] < need && need <= eb[q + 1]) {
            spre = (pre << 8) | (uint32_t)(4 * tid + q);
            sneedS = need - eb[q];
          }
      }
      __syncthreads();
      pre = spre; need = sneedS;
      __syncthreads();
    }
    T2 = pre;
  }

  for (int t = tid; t < GCAP; t += 1024) {
    bool take = ((accm[t >> 6] >> (t & 63)) & 1ull) && (lk[t] <= T2);
    wave_compact32(take, (uint32_t)t, &scnt2, lsel, 512u);
  }
  __syncthreads();
  uint32_t cnt = min(scnt2, 512u);
  if (tid < (int)cnt) kkbuf[tid] = lk[lsel[tid]];
  __syncthreads();
  if (tid < (int)cnt) {
    unsigned long long k0 = kkbuf[tid];
    uint32_t rank = 0;
    #pragma unroll 8
    for (uint32_t p = 0; p < 512u; ++p) rank += (kkbuf[p] < k0) ? 1u : 0u;
    if (rank < (uint32_t)KPOST) {
      int i = (int)lsel[tid];
      out[rank * 6 + 0] = x1a[i];
      out[rank * 6 + 1] = y1a[i];
      out[rank * 6 + 2] = x2a[i];
      out[rank * 6 + 3] = y2a[i];
      out[rank * 6 + 4] = vala[i];
      out[rank * 6 + 5] = (float)laba[i];
    }
  }
}

extern "C" void kernel_launch(void* const* d_in, const int* in_sizes, int n_in,
                              void* d_out, int out_size, void* d_ws, size_t ws_size,
                              hipStream_t stream) {
  const float* boxes = (const float*)d_in[0];
  const float* cls   = (const float*)d_in[1];
  float* out = (float*)d_out;
  char* ws = (char*)d_ws;

  uint32_t* keys = (uint32_t*)(ws + OFF_KEYS);
  uint32_t* pairs = (uint32_t*)(ws + OFF_PAIRS);
  float* x1a = (float*)(ws + OFF_ARR);
  float* y1a = x1a + GCAP;
  float* x2a = y1a + GCAP;
  float* y2a = x2a + GCAP;
  float* vala = y2a + GCAP;
  int* laba = (int*)(vala + GCAP);
  unsigned long long* skg = (unsigned long long*)(laba + GCAP);
  uint8_t* labs = (uint8_t*)(ws + OFF_LAB);
  uint32_t* zbase = (uint32_t*)(ws + OFF_ZERO);
  uint32_t* hist0 = zbase + ZW_HIST0;
  uint32_t* hist2 = zbase + ZW_HIST2;
  uint32_t* hist16 = zbase + ZW_HIST16;
  uint32_t* state = zbase + ZW_STATE;
  uint32_t* selcnt = state;      // state[0]
  uint32_t* paircnt = state + 1; // state[1]

  hipMemsetAsync(ws + OFF_ZERO, 0, ZERO_BYTES, stream);
  k_score<<<1024, 256, 0, stream>>>(cls, keys, labs, hist0, hist16);
  k_hist2<<<1024, 256, 0, stream>>>(keys, hist0, hist16, hist2,
                                    x1a, y1a, x2a, y2a, vala, laba, skg);
  k_selgather<<<1024, 256, 0, stream>>>(keys, boxes, labs, hist0, hist16, hist2,
                                        selcnt, x1a, y1a, x2a, y2a, vala, laba, skg);
  k_pairs<<<dim3(PROWS, PROWS), 64, 0, stream>>>(x1a, y1a, x2a, y2a, skg, paircnt, pairs);
  k_fix<<<1, 1024, 0, stream>>>(state, pairs, x1a, y1a, x2a, y2a, vala, laba, skg, out);
}

// Round 9
// 223.588 us; speedup vs baseline: 22.7928x; 1.1961x over previous
//
#include <hip/hip_runtime.h>
#include <stdint.h>

#define NBOX 2000000
#define NCLS 10
#define KPRE 4096
#define KPOST 500
#define GCAP 6144        // gathered candidate cap (>= 4096 + p24 boundary bucket)
#define NMW  (GCAP / 64) // 96 mask words
#define PCAP 131072      // pair cap
#define LPC  16384       // LDS pair cache in k_fix (64 KB)
#define PROWS (GCAP / 64) // 96 tile rows
#define BSEL 4096        // per-block select cap in k_selgather LDS

// ---- workspace layout (bytes) ----
#define OFF_KEYS  ((size_t)0)                          // NBOX*4 = 8,000,000
#define OFF_PAIRS ((size_t)8000000)                    // PCAP*4
#define OFF_ARR   (OFF_PAIRS + (size_t)PCAP * 4)       // 32 B * GCAP
#define OFF_LAB   (OFF_ARR + (size_t)GCAP * 32)        // NBOX u8
#define OFF_ZERO  (OFF_LAB + (size_t)NBOX)
// zero region (words): hist0[256] | hist2[256] | hist16[65536] | state[16]
#define ZW_HIST0  0
#define ZW_HIST2  256
#define ZW_HIST16 512
#define ZW_STATE  (512 + 65536)
#define ZERO_WORDS (ZW_STATE + 16)
#define ZERO_BYTES ((size_t)ZERO_WORDS * 4)

// ord-space constant: scores in [0.5,1) have (u>>16) in [0x4080, 0x40FF] (128 hot bins)
#define HOTBASE 0x4080u

__device__ __forceinline__ uint32_t f2ord(float f) {
  uint32_t b = __float_as_uint(f);
  return (b & 0x80000000u) ? ~b : (b | 0x80000000u);
}
__device__ __forceinline__ float ord2f(uint32_t ord) {
  uint32_t b = (ord & 0x80000000u) ? (ord ^ 0x80000000u) : ~ord;
  return __uint_as_float(b);
}

__device__ __forceinline__ unsigned long long shflx64(unsigned long long v, int mask) {
  union { unsigned long long u; int i[2]; } a; a.u = v;
  a.i[0] = __shfl_xor(a.i[0], mask, 64);
  a.i[1] = __shfl_xor(a.i[1], mask, 64);
  return a.u;
}

// full-wave (lanes 0..63): bucket of the need-th smallest in h[256] (global or LDS)
__device__ __forceinline__ void wave_bucket(const uint32_t* __restrict__ h, uint32_t need,
                                            uint32_t* bin_out, uint32_t* nd_out) {
  int l = threadIdx.x & 63;
  uint4 h4 = reinterpret_cast<const uint4*>(h)[l];
  uint32_t s = h4.x + h4.y + h4.z + h4.w;
  uint32_t p = s;
  #pragma unroll
  for (int d = 1; d < 64; d <<= 1) {
    uint32_t v = __shfl_up(p, d, 64);
    if (l >= d) p += v;
  }
  uint32_t e0 = p - s, e1 = e0 + h4.x, e2 = e1 + h4.y, e3 = e2 + h4.z, e4 = e3 + h4.w;
  uint32_t eb[5] = {e0, e1, e2, e3, e4};
  uint32_t bin = 0xFFFFFFFFu, nd = 1;
  #pragma unroll
  for (int q = 0; q < 4; ++q)
    if (eb[q] < need && need <= eb[q + 1]) { bin = (uint32_t)(4 * l + q); nd = need - eb[q]; }
  unsigned long long mm = __ballot(bin != 0xFFFFFFFFu);
  int src = mm ? __builtin_ctzll(mm) : 0;
  *bin_out = (uint32_t)__shfl((int)bin, src);
  *nd_out  = (uint32_t)__shfl((int)nd, src);
}

__device__ __forceinline__ void wave_compact32(bool take, uint32_t key,
                                               uint32_t* counter, uint32_t* buf,
                                               uint32_t cap) {
  unsigned long long mm = __ballot(take);
  if (take) {
    int lane = threadIdx.x & 63;
    unsigned long long lt = (lane == 0) ? 0ull : (~0ull >> (64 - lane));
    int rank = __builtin_popcountll(mm & lt);
    int leader = __builtin_ctzll(mm);
    uint32_t base = 0;
    if (rank == 0) base = atomicAdd(counter, (uint32_t)__builtin_popcountll(mm));
    base = __shfl(base, leader);
    uint32_t pos = base + (uint32_t)rank;
    if (pos < cap) buf[pos] = key;
  }
}

// tree max-of-10 with first-max index (strict > merges == sequential argmax)
__device__ __forceinline__ void tree10(float v0, float v1, float v2, float v3, float v4,
                                       float v5, float v6, float v7, float v8, float v9,
                                       float* mv, int* mi) {
  float b0, b1, b2, b3, b4; int j0, j1, j2, j3, j4;
  if (v1 > v0) { b0 = v1; j0 = 1; } else { b0 = v0; j0 = 0; }
  if (v3 > v2) { b1 = v3; j1 = 3; } else { b1 = v2; j1 = 2; }
  if (v5 > v4) { b2 = v5; j2 = 5; } else { b2 = v4; j2 = 4; }
  if (v7 > v6) { b3 = v7; j3 = 7; } else { b3 = v6; j3 = 6; }
  if (v9 > v8) { b4 = v9; j4 = 9; } else { b4 = v8; j4 = 8; }
  if (b1 > b0) { b0 = b1; j0 = j1; }
  if (b3 > b2) { b2 = b3; j2 = j3; }
  if (b2 > b0) { b0 = b2; j0 = j2; }
  if (b4 > b0) { b0 = b4; j0 = j4; }
  *mv = b0; *mi = j0;
}

// ---------------- kernels ----------------

// 1) score pass: cls (80 MB) -> ord keys + labels; hist0 (byte0) + hist16 (16-bit prefix).
//    Hot prefix range [0x4080,0x4100) handled in LDS; rare bins via global atomics.
__global__ void k_score(const float* __restrict__ cls, uint32_t* __restrict__ keys,
                        uint8_t* __restrict__ labs, uint32_t* __restrict__ hist0,
                        uint32_t* __restrict__ hist16) {
  __shared__ uint32_t lh0[256];
  __shared__ uint32_t lhr[128];
  for (int i = threadIdx.x; i < 256; i += blockDim.x) lh0[i] = 0;
  for (int i = threadIdx.x; i < 128; i += blockDim.x) lhr[i] = 0;
  __syncthreads();
  const int nvec = NBOX / 4;
  const float4* cp = reinterpret_cast<const float4*>(cls);
  const int pstr = NBOX / 4;
  for (int v = blockIdx.x * blockDim.x + threadIdx.x; v < nvec; v += gridDim.x * blockDim.x) {
    float4 x0 = cp[v];
    float4 x1 = cp[pstr * 1 + v];
    float4 x2 = cp[pstr * 2 + v];
    float4 x3 = cp[pstr * 3 + v];
    float4 x4 = cp[pstr * 4 + v];
    float4 x5 = cp[pstr * 5 + v];
    float4 x6 = cp[pstr * 6 + v];
    float4 x7 = cp[pstr * 7 + v];
    float4 x8 = cp[pstr * 8 + v];
    float4 x9 = cp[pstr * 9 + v];
    uint32_t u4[4]; int l4[4];
    float mv; int mi;
    tree10(x0.x, x1.x, x2.x, x3.x, x4.x, x5.x, x6.x, x7.x, x8.x, x9.x, &mv, &mi);
    { float ms = (mv >= 0.1f) ? mv : -1.0f; u4[0] = ~f2ord(ms); l4[0] = mi; }
    tree10(x0.y, x1.y, x2.y, x3.y, x4.y, x5.y, x6.y, x7.y, x8.y, x9.y, &mv, &mi);
    { float ms = (mv >= 0.1f) ? mv : -1.0f; u4[1] = ~f2ord(ms); l4[1] = mi; }
    tree10(x0.z, x1.z, x2.z, x3.z, x4.z, x5.z, x6.z, x7.z, x8.z, x9.z, &mv, &mi);
    { float ms = (mv >= 0.1f) ? mv : -1.0f; u4[2] = ~f2ord(ms); l4[2] = mi; }
    tree10(x0.w, x1.w, x2.w, x3.w, x4.w, x5.w, x6.w, x7.w, x8.w, x9.w, &mv, &mi);
    { float ms = (mv >= 0.1f) ? mv : -1.0f; u4[3] = ~f2ord(ms); l4[3] = mi; }
    #pragma unroll
    for (int q = 0; q < 4; ++q) {
      uint32_t b16 = u4[q] >> 16;
      uint32_t rel = b16 - HOTBASE;
      if (rel < 128u) atomicAdd(&lhr[rel], 1u);
      else { atomicAdd(&hist16[b16], 1u); atomicAdd(&lh0[b16 >> 8], 1u); }
    }
    reinterpret_cast<uint4*>(keys)[v] = make_uint4(u4[0], u4[1], u4[2], u4[3]);
    uchar4 lb; lb.x = (uint8_t)l4[0]; lb.y = (uint8_t)l4[1];
    lb.z = (uint8_t)l4[2]; lb.w = (uint8_t)l4[3];
    reinterpret_cast<uchar4*>(labs)[v] = lb;
  }
  __syncthreads();
  for (int i = threadIdx.x; i < 128; i += blockDim.x) {
    uint32_t c = lhr[i];
    if (c) { atomicAdd(&hist16[HOTBASE + i], c); atomicAdd(&lh0[HOTBASE >> 8], c); }
  }
  __syncthreads();
  for (int i = threadIdx.x; i < 256; i += blockDim.x)
    if (lh0[i]) atomicAdd(&hist0[i], lh0[i]);
}

// 2) keys pass: byte2 histogram among prefix == p16 (p16 computed inline, exact);
//    also sentinel-inits the gather arrays.
__global__ void k_hist2(const uint32_t* __restrict__ keys,
                        const uint32_t* __restrict__ hist0,
                        const uint32_t* __restrict__ hist16,
                        uint32_t* __restrict__ hist2,
                        float* __restrict__ x1a, float* __restrict__ y1a,
                        float* __restrict__ x2a, float* __restrict__ y2a,
                        float* __restrict__ vala, int* __restrict__ laba,
                        unsigned long long* __restrict__ skg) {
  __shared__ uint32_t lh[256];
  __shared__ uint32_t sp16;
  if (threadIdx.x < 64) {
    uint32_t b1, nd1, b2, nd2;
    wave_bucket(hist0, KPRE, &b1, &nd1);
    wave_bucket(hist16 + ((size_t)b1 << 8), nd1, &b2, &nd2);
    if (threadIdx.x == 0) sp16 = (b1 << 8) | b2;
  }
  for (int i = threadIdx.x; i < 256; i += blockDim.x) lh[i] = 0;
  __syncthreads();
  uint32_t p16 = sp16;
  const int nvec = NBOX / 4;
  int gtid = blockIdx.x * blockDim.x + threadIdx.x;
  int gtot = gridDim.x * blockDim.x;
  for (int v = gtid; v < nvec; v += gtot) {
    uint4 kv = reinterpret_cast<const uint4*>(keys)[v];
    if ((kv.x >> 16) == p16) atomicAdd(&lh[(kv.x >> 8) & 255u], 1u);
    if ((kv.y >> 16) == p16) atomicAdd(&lh[(kv.y >> 8) & 255u], 1u);
    if ((kv.z >> 16) == p16) atomicAdd(&lh[(kv.z >> 8) & 255u], 1u);
    if ((kv.w >> 16) == p16) atomicAdd(&lh[(kv.w >> 8) & 255u], 1u);
  }
  for (int t = gtid; t < GCAP; t += gtot) {
    x1a[t] = 0.0f; y1a[t] = 0.0f; x2a[t] = 0.0f; y2a[t] = 0.0f;
    vala[t] = -1.0f; laba[t] = 0; skg[t] = ~0ull;
  }
  __syncthreads();
  for (int i = threadIdx.x; i < 256; i += blockDim.x)
    if (lh[i]) atomicAdd(&hist2[i], lh[i]);
}

// 3) keys pass: select (u>>8) <= p24 (superset of exact top-4096, <= GCAP in practice).
//    TWO-LEVEL allocation: block-local LDS compaction, ONE global atomicAdd per block
//    (kills the single-cacheline wave-atomic serialization measured in round 7:
//     ~4.4K device-scope RMWs on one line ~= 50 us).
__global__ void k_selgather(const uint32_t* __restrict__ keys,
                            const float* __restrict__ boxes, const uint8_t* __restrict__ labs,
                            const uint32_t* __restrict__ hist0,
                            const uint32_t* __restrict__ hist16,
                            const uint32_t* __restrict__ hist2,
                            uint32_t* __restrict__ selcnt,
                            float* __restrict__ x1a, float* __restrict__ y1a,
                            float* __restrict__ x2a, float* __restrict__ y2a,
                            float* __restrict__ vala, int* __restrict__ laba,
                            unsigned long long* __restrict__ skg) {
  __shared__ uint32_t sp24, bcnt, bbase;
  __shared__ uint32_t lu[BSEL];
  __shared__ uint32_t li[BSEL];
  if (threadIdx.x < 64) {
    uint32_t b1, nd1, b2, nd2, b3, nd3;
    wave_bucket(hist0, KPRE, &b1, &nd1);
    wave_bucket(hist16 + ((size_t)b1 << 8), nd1, &b2, &nd2);
    wave_bucket(hist2, nd2, &b3, &nd3);
    if (threadIdx.x == 0) sp24 = (((b1 << 8) | b2) << 8) | b3;
  }
  if (threadIdx.x == 0) bcnt = 0;
  __syncthreads();
  uint32_t p24 = sp24;
  const int nvec = NBOX / 4;
  for (int v = blockIdx.x * blockDim.x + threadIdx.x; v < nvec; v += gridDim.x * blockDim.x) {
    uint4 kv = reinterpret_cast<const uint4*>(keys)[v];
    uint32_t us[4] = {kv.x, kv.y, kv.z, kv.w};
    #pragma unroll
    for (int q = 0; q < 4; ++q) {
      uint32_t u = us[q];
      if ((u >> 8) <= p24) {
        uint32_t p = atomicAdd(&bcnt, 1u);  // LDS atomic; takes are ~9/block
        if (p < (uint32_t)BSEL) { lu[p] = u; li[p] = (uint32_t)(4 * v + q); }
      }
    }
  }
  __syncthreads();
  if (threadIdx.x == 0) {
    uint32_t c = bcnt; if (c > (uint32_t)BSEL) c = (uint32_t)BSEL;
    bbase = c ? atomicAdd(selcnt, c) : 0u;  // ONE global RMW per block
    bcnt = c;
  }
  __syncthreads();
  uint32_t c = bcnt, base = bbase;
  for (uint32_t i = threadIdx.x; i < c; i += blockDim.x) {
    uint32_t pos = base + i;
    if (pos < (uint32_t)GCAP) {
      uint32_t idx = li[i];
      uint32_t u = lu[i];
      x1a[pos] = boxes[idx];
      y1a[pos] = boxes[(size_t)NBOX + idx];
      x2a[pos] = boxes[(size_t)2 * NBOX + idx];
      y2a[pos] = boxes[(size_t)3 * NBOX + idx];
      vala[pos] = ord2f(~u);
      laba[pos] = (int)labs[idx];
      skg[pos] = ((unsigned long long)u << 32) | idx;
    }
  }
}

// 4) suppression pairs: 96x96 triangular 64x64 tiles; sentinel boxes produce no pairs.
__global__ void k_pairs(const float* __restrict__ x1a, const float* __restrict__ y1a,
                        const float* __restrict__ x2a, const float* __restrict__ y2a,
                        const unsigned long long* __restrict__ skg,
                        uint32_t* __restrict__ paircnt, uint32_t* __restrict__ pairs) {
#pragma clang fp contract(off)
  int bx = blockIdx.x, by = blockIdx.y;
  if (bx < by) return;
  int t = threadIdx.x;  // 64 threads
  int i = by * 64 + t;
  __shared__ float sx1[64], sy1[64], sx2[64], sy2[64], sar[64];
  __shared__ unsigned long long sk[64];
  int j0 = bx * 64 + t;
  float cx1 = x1a[j0], cy1 = y1a[j0], cx2 = x2a[j0], cy2 = y2a[j0];
  sx1[t] = cx1; sy1[t] = cy1; sx2[t] = cx2; sy2[t] = cy2;
  sar[t] = fmaxf(cx2 - cx1, 0.0f) * fmaxf(cy2 - cy1, 0.0f);
  sk[t] = skg[j0];
  __syncthreads();
  float x1i = x1a[i], y1i = y1a[i], x2i = x2a[i], y2i = y2a[i];
  unsigned long long rk = skg[i];
  float ari = fmaxf(x2i - x1i, 0.0f) * fmaxf(y2i - y1i, 0.0f);
  unsigned long long w = 0ull;
  #pragma unroll 8
  for (int jj = 0; jj < 64; ++jj) {
    int j = bx * 64 + jj;
    float iw = fmaxf(fminf(x2i, sx2[jj]) - fmaxf(x1i, sx1[jj]), 0.0f);
    float ih = fmaxf(fminf(y2i, sy2[jj]) - fmaxf(y1i, sy1[jj]), 0.0f);
    float inter = iw * ih;
    float den = ((ari + sar[jj]) - inter) + 1e-8f;  // exact ref op order
    float iou = inter / den;
    if ((iou > 0.5f) && (j > i)) w |= (1ull << jj);
  }
  while (__ballot(w != 0ull)) {
    bool tk = (w != 0ull);
    uint32_t pr = 0;
    if (tk) {
      int b = __builtin_ctzll(w); w &= w - 1;
      int j = bx * 64 + b;
      bool i_sup = (rk < sk[b]);  // smaller key (higher score / lower orig idx) suppresses
      pr = i_sup ? (((uint32_t)i << 16) | (uint32_t)j)
                 : (((uint32_t)j << 16) | (uint32_t)i);
    }
    wave_compact32(tk, pr, paircnt, pairs, (uint32_t)PCAP);
  }
}

// 5) single block: exact top-4096 cut (radix) + Jacobi fixpoint + top-500 emit.
__global__ void __launch_bounds__(1024) k_fix(
    const uint32_t* __restrict__ state, const uint32_t* __restrict__ pairs,
    const float* __restrict__ x1a, const float* __restrict__ y1a,
    const float* __restrict__ x2a, const float* __restrict__ y2a,
    const float* __restrict__ vala, const int* __restrict__ laba,
    const unsigned long long* __restrict__ skg, float* __restrict__ out) {
  __shared__ unsigned long long lk[GCAP];
  __shared__ uint32_t lpair[LPC];
  __shared__ unsigned long long validm[NMW], accm[NMW];
  __shared__ uint32_t supp[NMW * 2];
  __shared__ uint32_t hsel[256];
  __shared__ uint32_t lsel[512];
  __shared__ unsigned long long kkbuf[512];
  __shared__ uint32_t chg, scnt2, sneedS;
  __shared__ unsigned long long spre;
  __shared__ uint32_t orlo, orhi, andlo, andhi;
  int tid = threadIdx.x;
  int lane = tid & 63;

  uint32_t gc = state[0]; if (gc > (uint32_t)GCAP) gc = (uint32_t)GCAP;
  uint32_t np = state[1]; if (np > (uint32_t)PCAP) np = (uint32_t)PCAP;
  for (int t = tid; t < KPOST * 6; t += 1024) out[t] = 0.0f;
  if (tid < 512) kkbuf[tid] = ~0ull;
  for (int t = tid; t < GCAP; t += 1024) lk[t] = (t < (int)gc) ? skg[t] : ~0ull;
  bool plds = (np <= (uint32_t)LPC);
  if (plds) for (uint32_t p = (uint32_t)tid; p < np; p += 1024) lpair[p] = pairs[p];
  if (tid == 0) { orlo = 0; orhi = 0; andlo = ~0u; andhi = ~0u; scnt2 = 0; }
  __syncthreads();

  // radix #1: T1 = exact need1-th smallest key among gathered
  uint32_t need1 = (gc < (uint32_t)KPRE) ? gc : (uint32_t)KPRE;
  if (need1 == 0) return;
  {
    unsigned long long myor = 0ull, myand = ~0ull;
    for (int t = tid; t < (int)gc; t += 1024) {
      unsigned long long k = lk[t];
      myor |= k; myand &= k;
    }
    #pragma unroll
    for (int d = 1; d < 64; d <<= 1) { myor |= shflx64(myor, d); myand &= shflx64(myand, d); }
    if (lane == 0) {
      atomicOr(&orlo, (uint32_t)myor); atomicOr(&orhi, (uint32_t)(myor >> 32));
      atomicAnd(&andlo, (uint32_t)myand); atomicAnd(&andhi, (uint32_t)(myand >> 32));
    }
  }
  __syncthreads();
  unsigned long long T1;
  {
    unsigned long long vor = ((unsigned long long)orhi << 32) | orlo;
    unsigned long long vand = ((unsigned long long)andhi << 32) | andlo;
    unsigned long long diff = vor ^ vand;
    unsigned long long pre = 0;
    uint32_t need = need1;
    for (int b = 7; b >= 0; --b) {
      uint32_t db = (uint32_t)(diff >> (8 * b)) & 255u;
      if (db == 0) { pre = (pre << 8) | ((uint32_t)(vand >> (8 * b)) & 255u); continue; }
      if (tid < 256) hsel[tid] = 0;
      __syncthreads();
      for (int t = tid; t < (int)gc; t += 1024) {
        unsigned long long k = lk[t];
        bool pm = (b == 7) ? true : ((k >> (8 * b + 8)) == pre);
        if (pm) atomicAdd(&hsel[(uint32_t)(k >> (8 * b)) & 255u], 1u);
      }
      __syncthreads();
      if (tid < 64) {
        uint32_t c0 = hsel[4 * tid], c1 = hsel[4 * tid + 1],
                 c2 = hsel[4 * tid + 2], c3 = hsel[4 * tid + 3];
        uint32_t s = c0 + c1 + c2 + c3;
        uint32_t p = s;
        #pragma unroll
        for (int d = 1; d < 64; d <<= 1) {
          uint32_t v = __shfl_up(p, d, 64);
          if (tid >= d) p += v;
        }
        uint32_t e0 = p - s, e1 = e0 + c0, e2 = e1 + c1, e3 = e2 + c2, e4 = e3 + c3;
        uint32_t eb[5] = {e0, e1, e2, e3, e4};
        #pragma unroll
        for (int q = 0; q < 4; ++q)
          if (eb[q] < need && need <= eb[q + 1]) {
            spre = (pre << 8) | (uint32_t)(4 * tid + q);
            sneedS = need - eb[q];
          }
      }
      __syncthreads();
      pre = spre; need = sneedS;
      __syncthreads();
    }
    T1 = pre;
  }

  // validity: exact top-4096 member AND score >= 0.1
  for (int t = tid; t < GCAP; t += 1024) {
    unsigned long long k = lk[t];
    float v = ord2f(~(uint32_t)(k >> 32));
    bool ok = (k <= T1) && (v >= 0.1f);
    unsigned long long bm = __ballot(ok);
    if (lane == 0) { validm[t >> 6] = bm; accm[t >> 6] = bm; }
  }
  __syncthreads();

  // Jacobi fixpoint of A[i] = V[i] & forall (j->i): !A[j]  (== greedy NMS)
  while (true) {
    __syncthreads();
    if (tid < NMW * 2) supp[tid] = 0;
    if (tid == 0) chg = 0;
    __syncthreads();
    if (plds) {
      for (uint32_t p = (uint32_t)tid; p < np; p += 1024) {
        uint32_t pr = lpair[p];
        uint32_t i = pr >> 16, j = pr & 0xffffu;
        if ((accm[i >> 6] >> (i & 63)) & 1ull) atomicOr(&supp[j >> 5], 1u << (j & 31));
      }
    } else {
      for (uint32_t p = (uint32_t)tid; p < np; p += 1024) {
        uint32_t pr = pairs[p];
        uint32_t i = pr >> 16, j = pr & 0xffffu;
        if ((accm[i >> 6] >> (i & 63)) & 1ull) atomicOr(&supp[j >> 5], 1u << (j & 31));
      }
    }
    __syncthreads();
    if (tid < NMW) {
      unsigned long long s = ((unsigned long long)supp[2 * tid + 1] << 32) | supp[2 * tid];
      unsigned long long na = validm[tid] & ~s;
      if (na != accm[tid]) { accm[tid] = na; atomicOr(&chg, 1u); }
    }
    __syncthreads();
    if (chg == 0) break;
  }

  // ---- top-KPOST of survivors (radix narrowing) + rank emit ----
  if (tid == 0) {
    uint32_t ns = 0;
    for (int l = 0; l < NMW; ++l) ns += (uint32_t)__builtin_popcountll(accm[l]);
    sneedS = (ns < (uint32_t)KPOST) ? ns : (uint32_t)KPOST;
    orlo = 0; orhi = 0; andlo = ~0u; andhi = ~0u;
  }
  __syncthreads();
  uint32_t need0 = sneedS;
  if (need0 == 0) return;
  {
    unsigned long long myor = 0ull, myand = ~0ull;
    for (int t = tid; t < GCAP; t += 1024) {
      if ((accm[t >> 6] >> (t & 63)) & 1ull) {
        unsigned long long k = lk[t];
        myor |= k; myand &= k;
      }
    }
    #pragma unroll
    for (int d = 1; d < 64; d <<= 1) { myor |= shflx64(myor, d); myand &= shflx64(myand, d); }
    if (lane == 0) {
      atomicOr(&orlo, (uint32_t)myor); atomicOr(&orhi, (uint32_t)(myor >> 32));
      atomicAnd(&andlo, (uint32_t)myand); atomicAnd(&andhi, (uint32_t)(myand >> 32));
    }
  }
  __syncthreads();
  unsigned long long T2;
  {
    unsigned long long vor = ((unsigned long long)orhi << 32) | orlo;
    unsigned long long vand = ((unsigned long long)andhi << 32) | andlo;
    unsigned long long diff = vor ^ vand;
    unsigned long long pre = 0;
    uint32_t need = need0;
    for (int b = 7; b >= 0; --b) {
      uint32_t db = (uint32_t)(diff >> (8 * b)) & 255u;
      if (db == 0) { pre = (pre << 8) | ((uint32_t)(vand >> (8 * b)) & 255u); continue; }
      if (tid < 256) hsel[tid] = 0;
      __syncthreads();
      for (int t = tid; t < GCAP; t += 1024) {
        if ((accm[t >> 6] >> (t & 63)) & 1ull) {
          unsigned long long k = lk[t];
          bool pm = (b == 7) ? true : ((k >> (8 * b + 8)) == pre);
          if (pm) atomicAdd(&hsel[(uint32_t)(k >> (8 * b)) & 255u], 1u);
        }
      }
      __syncthreads();
      if (tid < 64) {
        uint32_t c0 = hsel[4 * tid], c1 = hsel[4 * tid + 1],
                 c2 = hsel[4 * tid + 2], c3 = hsel[4 * tid + 3];
        uint32_t s = c0 + c1 + c2 + c3;
        uint32_t p = s;
        #pragma unroll
        for (int d = 1; d < 64; d <<= 1) {
          uint32_t v = __shfl_up(p, d, 64);
          if (tid >= d) p += v;
        }
        uint32_t e0 = p - s, e1 = e0 + c0, e2 = e1 + c1, e3 = e2 + c2, e4 = e3 + c3;
        uint32_t eb[5] = {e0, e1, e2, e3, e4};
        #pragma unroll
        for (int q = 0; q < 4; ++q)
          if (eb[q] < need && need <= eb[q + 1]) {
            spre = (pre << 8) | (uint32_t)(4 * tid + q);
            sneedS = need - eb[q];
          }
      }
      __syncthreads();
      pre = spre; need = sneedS;
      __syncthreads();
    }
    T2 = pre;
  }

  for (int t = tid; t < GCAP; t += 1024) {
    bool take = ((accm[t >> 6] >> (t & 63)) & 1ull) && (lk[t] <= T2);
    wave_compact32(take, (uint32_t)t, &scnt2, lsel, 512u);
  }
  __syncthreads();
  uint32_t cnt = min(scnt2, 512u);
  if (tid < (int)cnt) kkbuf[tid] = lk[lsel[tid]];
  __syncthreads();
  if (tid < (int)cnt) {
    unsigned long long k0 = kkbuf[tid];
    uint32_t rank = 0;
    #pragma unroll 8
    for (uint32_t p = 0; p < 512u; ++p) rank += (kkbuf[p] < k0) ? 1u : 0u;
    if (rank < (uint32_t)KPOST) {
      int i = (int)lsel[tid];
      out[rank * 6 + 0] = x1a[i];
      out[rank * 6 + 1] = y1a[i];
      out[rank * 6 + 2] = x2a[i];
      out[rank * 6 + 3] = y2a[i];
      out[rank * 6 + 4] = vala[i];
      out[rank * 6 + 5] = (float)laba[i];
    }
  }
}

extern "C" void kernel_launch(void* const* d_in, const int* in_sizes, int n_in,
                              void* d_out, int out_size, void* d_ws, size_t ws_size,
                              hipStream_t stream) {
  const float* boxes = (const float*)d_in[0];
  const float* cls   = (const float*)d_in[1];
  float* out = (float*)d_out;
  char* ws = (char*)d_ws;

  uint32_t* keys = (uint32_t*)(ws + OFF_KEYS);
  uint32_t* pairs = (uint32_t*)(ws + OFF_PAIRS);
  float* x1a = (float*)(ws + OFF_ARR);
  float* y1a = x1a + GCAP;
  float* x2a = y1a + GCAP;
  float* y2a = x2a + GCAP;
  float* vala = y2a + GCAP;
  int* laba = (int*)(vala + GCAP);
  unsigned long long* skg = (unsigned long long*)(laba + GCAP);
  uint8_t* labs = (uint8_t*)(ws + OFF_LAB);
  uint32_t* zbase = (uint32_t*)(ws + OFF_ZERO);
  uint32_t* hist0 = zbase + ZW_HIST0;
  uint32_t* hist2 = zbase + ZW_HIST2;
  uint32_t* hist16 = zbase + ZW_HIST16;
  uint32_t* state = zbase + ZW_STATE;
  uint32_t* selcnt = state;      // state[0]
  uint32_t* paircnt = state + 1; // state[1]

  hipMemsetAsync(ws + OFF_ZERO, 0, ZERO_BYTES, stream);
  k_score<<<1024, 256, 0, stream>>>(cls, keys, labs, hist0, hist16);
  k_hist2<<<512, 256, 0, stream>>>(keys, hist0, hist16, hist2,
                                   x1a, y1a, x2a, y2a, vala, laba, skg);
  k_selgather<<<512, 256, 0, stream>>>(keys, boxes, labs, hist0, hist16, hist2,
                                       selcnt, x1a, y1a, x2a, y2a, vala, laba, skg);
  k_pairs<<<dim3(PROWS, PROWS), 64, 0, stream>>>(x1a, y1a, x2a, y2a, skg, paircnt, pairs);
  k_fix<<<1, 1024, 0, stream>>>(state, pairs, x1a, y1a, x2a, y2a, vala, laba, skg, out);
}

// Round 10
// 218.576 us; speedup vs baseline: 23.3154x; 1.0229x over previous
//
#include <hip/hip_runtime.h>
#include <stdint.h>

#define NBOX 2000000
#define NCLS 10
#define KPRE 4096
#define KPOST 500
#define GCAP 6144        // gathered candidate cap (>= 4096 + p24 boundary bucket)
#define NMW  (GCAP / 64) // 96 mask words
#define PCAP 131072      // pair cap
#define LPC  16384       // LDS pair cache in fix phase (64 KB)
#define MSEL 2048        // per-block select cap in k_mid LDS
#define NBLKM 256        // k_mid / k_tail blocks (<= capacity => co-resident)
#define NWAV 16          // waves per 1024-thread block

// ---- workspace layout (bytes) ----
#define OFF_KEYS  ((size_t)0)                          // NBOX*4 = 8,000,000
#define OFF_PAIRS ((size_t)8000000)                    // PCAP*4
#define OFF_ARR   (OFF_PAIRS + (size_t)PCAP * 4)       // 32 B * GCAP
#define OFF_LAB   (OFF_ARR + (size_t)GCAP * 32)        // NBOX u8
#define OFF_ZERO  (OFF_LAB + (size_t)NBOX)
// zero region (words): hist0[256] | hist2[256] | hist16[65536] | state[544]
#define ZW_HIST0  0
#define ZW_HIST2  256
#define ZW_HIST16 512
#define ZW_STATE  (512 + 65536)
// state words: [0]=selcnt [1]=paircnt [2]=rel1 | [16..271]=flags1 | [272..527]=flags2
#define SW_REL1   2
#define SW_FLAGS1 16
#define SW_FLAGS2 272
#define ZERO_WORDS (ZW_STATE + 544)
#define ZERO_BYTES ((size_t)ZERO_WORDS * 4)

// ord-space constant: scores in [0.5,1) have (u>>16) in [0x4080, 0x40FF] (128 hot bins)
#define HOTBASE 0x4080u

__device__ __forceinline__ uint32_t f2ord(float f) {
  uint32_t b = __float_as_uint(f);
  return (b & 0x80000000u) ? ~b : (b | 0x80000000u);
}
__device__ __forceinline__ float ord2f(uint32_t ord) {
  uint32_t b = (ord & 0x80000000u) ? (ord ^ 0x80000000u) : ~ord;
  return __uint_as_float(b);
}

__device__ __forceinline__ unsigned long long shflx64(unsigned long long v, int mask) {
  union { unsigned long long u; int i[2]; } a; a.u = v;
  a.i[0] = __shfl_xor(a.i[0], mask, 64);
  a.i[1] = __shfl_xor(a.i[1], mask, 64);
  return a.u;
}

// full grid barrier (256 co-resident blocks): per-block arrival flags (pure stores),
// block 0 aggregates and releases. Relaxed polls; one fence each side. (Proven r5.)
__device__ __forceinline__ void mid_bar(uint32_t* flags1, uint32_t* rel1) {
  __syncthreads();
  int tid = threadIdx.x;
  if (blockIdx.x == 0) {
    if (tid >= 1 && tid < NBLKM) {
      while (!__hip_atomic_load(&flags1[tid], __ATOMIC_RELAXED, __HIP_MEMORY_SCOPE_AGENT))
        __builtin_amdgcn_s_sleep(2);
    }
    __syncthreads();
    if (tid == 0) {
      __threadfence();
      __hip_atomic_store(rel1, 1u, __ATOMIC_RELAXED, __HIP_MEMORY_SCOPE_AGENT);
    }
    __syncthreads();
  } else {
    if (tid == 0) {
      __threadfence();
      __hip_atomic_store(&flags1[blockIdx.x], 1u, __ATOMIC_RELAXED, __HIP_MEMORY_SCOPE_AGENT);
      while (!__hip_atomic_load(rel1, __ATOMIC_RELAXED, __HIP_MEMORY_SCOPE_AGENT))
        __builtin_amdgcn_s_sleep(2);
      __threadfence();
    }
    __syncthreads();
  }
}

// full-wave (lanes 0..63): bucket of the need-th smallest in h[256] (global or LDS)
__device__ __forceinline__ void wave_bucket(const uint32_t* __restrict__ h, uint32_t need,
                                            uint32_t* bin_out, uint32_t* nd_out) {
  int l = threadIdx.x & 63;
  uint4 h4 = reinterpret_cast<const uint4*>(h)[l];
  uint32_t s = h4.x + h4.y + h4.z + h4.w;
  uint32_t p = s;
  #pragma unroll
  for (int d = 1; d < 64; d <<= 1) {
    uint32_t v = __shfl_up(p, d, 64);
    if (l >= d) p += v;
  }
  uint32_t e0 = p - s, e1 = e0 + h4.x, e2 = e1 + h4.y, e3 = e2 + h4.z, e4 = e3 + h4.w;
  uint32_t eb[5] = {e0, e1, e2, e3, e4};
  uint32_t bin = 0xFFFFFFFFu, nd = 1;
  #pragma unroll
  for (int q = 0; q < 4; ++q)
    if (eb[q] < need && need <= eb[q + 1]) { bin = (uint32_t)(4 * l + q); nd = need - eb[q]; }
  unsigned long long mm = __ballot(bin != 0xFFFFFFFFu);
  int src = mm ? __builtin_ctzll(mm) : 0;
  *bin_out = (uint32_t)__shfl((int)bin, src);
  *nd_out  = (uint32_t)__shfl((int)nd, src);
}

__device__ __forceinline__ void wave_compact32(bool take, uint32_t key,
                                               uint32_t* counter, uint32_t* buf,
                                               uint32_t cap) {
  unsigned long long mm = __ballot(take);
  if (take) {
    int lane = threadIdx.x & 63;
    unsigned long long lt = (lane == 0) ? 0ull : (~0ull >> (64 - lane));
    int rank = __builtin_popcountll(mm & lt);
    int leader = __builtin_ctzll(mm);
    uint32_t base = 0;
    if (rank == 0) base = atomicAdd(counter, (uint32_t)__builtin_popcountll(mm));
    base = __shfl(base, leader);
    uint32_t pos = base + (uint32_t)rank;
    if (pos < cap) buf[pos] = key;
  }
}

// tree max-of-10 with first-max index (strict > merges == sequential argmax)
__device__ __forceinline__ void tree10(float v0, float v1, float v2, float v3, float v4,
                                       float v5, float v6, float v7, float v8, float v9,
                                       float* mv, int* mi) {
  float b0, b1, b2, b3, b4; int j0, j1, j2, j3, j4;
  if (v1 > v0) { b0 = v1; j0 = 1; } else { b0 = v0; j0 = 0; }
  if (v3 > v2) { b1 = v3; j1 = 3; } else { b1 = v2; j1 = 2; }
  if (v5 > v4) { b2 = v5; j2 = 5; } else { b2 = v4; j2 = 4; }
  if (v7 > v6) { b3 = v7; j3 = 7; } else { b3 = v6; j3 = 6; }
  if (v9 > v8) { b4 = v9; j4 = 9; } else { b4 = v8; j4 = 8; }
  if (b1 > b0) { b0 = b1; j0 = j1; }
  if (b3 > b2) { b2 = b3; j2 = j3; }
  if (b2 > b0) { b0 = b2; j0 = j2; }
  if (b4 > b0) { b0 = b4; j0 = j4; }
  *mv = b0; *mi = j0;
}

// ---------------- kernels ----------------

// 1) score pass: cls (80 MB) -> ord keys + labels; hist0 (byte0) + hist16 (16-bit prefix).
__global__ void k_score(const float* __restrict__ cls, uint32_t* __restrict__ keys,
                        uint8_t* __restrict__ labs, uint32_t* __restrict__ hist0,
                        uint32_t* __restrict__ hist16) {
  __shared__ uint32_t lh0[256];
  __shared__ uint32_t lhr[128];
  for (int i = threadIdx.x; i < 256; i += blockDim.x) lh0[i] = 0;
  for (int i = threadIdx.x; i < 128; i += blockDim.x) lhr[i] = 0;
  __syncthreads();
  const int nvec = NBOX / 4;
  const float4* cp = reinterpret_cast<const float4*>(cls);
  const int pstr = NBOX / 4;
  for (int v = blockIdx.x * blockDim.x + threadIdx.x; v < nvec; v += gridDim.x * blockDim.x) {
    float4 x0 = cp[v];
    float4 x1 = cp[pstr * 1 + v];
    float4 x2 = cp[pstr * 2 + v];
    float4 x3 = cp[pstr * 3 + v];
    float4 x4 = cp[pstr * 4 + v];
    float4 x5 = cp[pstr * 5 + v];
    float4 x6 = cp[pstr * 6 + v];
    float4 x7 = cp[pstr * 7 + v];
    float4 x8 = cp[pstr * 8 + v];
    float4 x9 = cp[pstr * 9 + v];
    uint32_t u4[4]; int l4[4];
    float mv; int mi;
    tree10(x0.x, x1.x, x2.x, x3.x, x4.x, x5.x, x6.x, x7.x, x8.x, x9.x, &mv, &mi);
    { float ms = (mv >= 0.1f) ? mv : -1.0f; u4[0] = ~f2ord(ms); l4[0] = mi; }
    tree10(x0.y, x1.y, x2.y, x3.y, x4.y, x5.y, x6.y, x7.y, x8.y, x9.y, &mv, &mi);
    { float ms = (mv >= 0.1f) ? mv : -1.0f; u4[1] = ~f2ord(ms); l4[1] = mi; }
    tree10(x0.z, x1.z, x2.z, x3.z, x4.z, x5.z, x6.z, x7.z, x8.z, x9.z, &mv, &mi);
    { float ms = (mv >= 0.1f) ? mv : -1.0f; u4[2] = ~f2ord(ms); l4[2] = mi; }
    tree10(x0.w, x1.w, x2.w, x3.w, x4.w, x5.w, x6.w, x7.w, x8.w, x9.w, &mv, &mi);
    { float ms = (mv >= 0.1f) ? mv : -1.0f; u4[3] = ~f2ord(ms); l4[3] = mi; }
    #pragma unroll
    for (int q = 0; q < 4; ++q) {
      uint32_t b16 = u4[q] >> 16;
      uint32_t rel = b16 - HOTBASE;
      if (rel < 128u) atomicAdd(&lhr[rel], 1u);
      else { atomicAdd(&hist16[b16], 1u); atomicAdd(&lh0[b16 >> 8], 1u); }
    }
    reinterpret_cast<uint4*>(keys)[v] = make_uint4(u4[0], u4[1], u4[2], u4[3]);
    uchar4 lb; lb.x = (uint8_t)l4[0]; lb.y = (uint8_t)l4[1];
    lb.z = (uint8_t)l4[2]; lb.w = (uint8_t)l4[3];
    reinterpret_cast<uchar4*>(labs)[v] = lb;
  }
  __syncthreads();
  for (int i = threadIdx.x; i < 128; i += blockDim.x) {
    uint32_t c = lhr[i];
    if (c) { atomicAdd(&hist16[HOTBASE + i], c); atomicAdd(&lh0[HOTBASE >> 8], c); }
  }
  __syncthreads();
  for (int i = threadIdx.x; i < 256; i += blockDim.x)
    if (lh0[i]) atomicAdd(&hist0[i], lh0[i]);
}

// 2) k_mid (256 blocks x 1024): phase H = byte2 hist among prefix==p16 + sentinel init;
//    grid barrier; phase S = p24 + two-level select + gather into final slots.
__global__ void __launch_bounds__(1024) k_mid(
    const uint32_t* __restrict__ keys,
    const float* __restrict__ boxes, const uint8_t* __restrict__ labs,
    const uint32_t* __restrict__ hist0, const uint32_t* __restrict__ hist16,
    uint32_t* __restrict__ hist2, uint32_t* __restrict__ state,
    float* __restrict__ x1a, float* __restrict__ y1a,
    float* __restrict__ x2a, float* __restrict__ y2a,
    float* __restrict__ vala, int* __restrict__ laba,
    unsigned long long* __restrict__ skg) {
  __shared__ uint32_t lh[256];
  __shared__ uint32_t lu[MSEL];
  __shared__ uint32_t li[MSEL];
  __shared__ uint32_t sp16, sp24, bcnt, bbase;
  int tid = threadIdx.x, blk = blockIdx.x;
  int gtid = blk * 1024 + tid;
  const int gtot = NBLKM * 1024;
  const int nvec = NBOX / 4;
  uint32_t* selcnt = state;
  uint32_t* flags1 = state + SW_FLAGS1;
  uint32_t* rel1 = state + SW_REL1;

  // ---- phase H: byte2 histogram among prefix == p16; sentinel-init gather arrays ----
  if (tid < 64) {
    uint32_t b1, nd1, b2, nd2;
    wave_bucket(hist0, KPRE, &b1, &nd1);
    wave_bucket(hist16 + ((size_t)b1 << 8), nd1, &b2, &nd2);
    if (tid == 0) sp16 = (b1 << 8) | b2;
  }
  for (int i = tid; i < 256; i += 1024) lh[i] = 0;
  __syncthreads();
  uint32_t p16 = sp16;
  for (int v = gtid; v < nvec; v += gtot) {
    uint4 kv = reinterpret_cast<const uint4*>(keys)[v];
    if ((kv.x >> 16) == p16) atomicAdd(&lh[(kv.x >> 8) & 255u], 1u);
    if ((kv.y >> 16) == p16) atomicAdd(&lh[(kv.y >> 8) & 255u], 1u);
    if ((kv.z >> 16) == p16) atomicAdd(&lh[(kv.z >> 8) & 255u], 1u);
    if ((kv.w >> 16) == p16) atomicAdd(&lh[(kv.w >> 8) & 255u], 1u);
  }
  for (int t = gtid; t < GCAP; t += gtot) {
    x1a[t] = 0.0f; y1a[t] = 0.0f; x2a[t] = 0.0f; y2a[t] = 0.0f;
    vala[t] = -1.0f; laba[t] = 0; skg[t] = ~0ull;
  }
  __syncthreads();
  for (int i = tid; i < 256; i += 1024)
    if (lh[i]) atomicAdd(&hist2[i], lh[i]);

  mid_bar(flags1, rel1);

  // ---- phase S: p24 + two-level select + gather ----
  if (tid < 64) {
    uint32_t b1, nd1, b2, nd2, b3, nd3;
    wave_bucket(hist0, KPRE, &b1, &nd1);
    wave_bucket(hist16 + ((size_t)b1 << 8), nd1, &b2, &nd2);
    wave_bucket(hist2, nd2, &b3, &nd3);
    if (tid == 0) sp24 = (((b1 << 8) | b2) << 8) | b3;
  }
  if (tid == 0) bcnt = 0;
  __syncthreads();
  uint32_t p24 = sp24;
  for (int v = gtid; v < nvec; v += gtot) {
    uint4 kv = reinterpret_cast<const uint4*>(keys)[v];
    uint32_t us[4] = {kv.x, kv.y, kv.z, kv.w};
    #pragma unroll
    for (int q = 0; q < 4; ++q) {
      uint32_t u = us[q];
      if ((u >> 8) <= p24) {
        uint32_t p = atomicAdd(&bcnt, 1u);  // LDS atomic; ~17 takes/block
        if (p < (uint32_t)MSEL) { lu[p] = u; li[p] = (uint32_t)(4 * v + q); }
      }
    }
  }
  __syncthreads();
  if (tid == 0) {
    uint32_t c = bcnt; if (c > (uint32_t)MSEL) c = (uint32_t)MSEL;
    bbase = c ? atomicAdd(selcnt, c) : 0u;  // ONE global RMW per block
    bcnt = c;
  }
  __syncthreads();
  uint32_t c = bcnt, base = bbase;
  for (uint32_t i = (uint32_t)tid; i < c; i += 1024) {
    uint32_t pos = base + i;
    if (pos < (uint32_t)GCAP) {
      uint32_t idx = li[i];
      uint32_t u = lu[i];
      x1a[pos] = boxes[idx];
      y1a[pos] = boxes[(size_t)NBOX + idx];
      x2a[pos] = boxes[(size_t)2 * NBOX + idx];
      y2a[pos] = boxes[(size_t)3 * NBOX + idx];
      vala[pos] = ord2f(~u);
      laba[pos] = (int)labs[idx];
      skg[pos] = ((unsigned long long)u << 32) | idx;
    }
  }
}

// 3) k_tail (256 blocks x 1024): phase E = triangular 64x64 suppression-pair tiles over
//    all waves; one-way join (deadlock-free: only block 0 waits); phase F (block 0) =
//    exact top-4096 cut + Jacobi fixpoint + top-500 emit.
__global__ void __launch_bounds__(1024) k_tail(
    uint32_t* __restrict__ state, uint32_t* __restrict__ pairs,
    const float* __restrict__ x1a, const float* __restrict__ y1a,
    const float* __restrict__ x2a, const float* __restrict__ y2a,
    const float* __restrict__ vala, const int* __restrict__ laba,
    const unsigned long long* __restrict__ skg, float* __restrict__ out) {
#pragma clang fp contract(off)
  __shared__ unsigned long long lk[GCAP];
  __shared__ uint32_t lpair[LPC];            // phase E: staging carved here (28 KB < 64 KB)
  __shared__ unsigned long long validm[NMW], accm[NMW];
  __shared__ uint32_t supp[NMW * 2];
  __shared__ uint32_t hsel[256];
  __shared__ uint32_t lsel[512];
  __shared__ unsigned long long kkbuf[512];
  __shared__ uint32_t chg, scnt2, sneedS;
  __shared__ unsigned long long spre;
  __shared__ uint32_t orlo, orhi, andlo, andhi;
  int tid = threadIdx.x, blk = blockIdx.x;
  int wid = tid >> 6, lane = tid & 63;
  uint32_t* paircnt = state + 1;
  uint32_t* flags2 = state + SW_FLAGS2;

  uint32_t gc = state[0]; if (gc > (uint32_t)GCAP) gc = (uint32_t)GCAP;

  // ---- phase E: suppression pairs over dynamic triangular tiles ----
  {
    int rows = (int)((gc + 63) >> 6);
    int NT = rows * (rows + 1) / 2;
    float* psx1 = (float*)lpair;
    float* psy1 = psx1 + NWAV * 64;
    float* psx2 = psy1 + NWAV * 64;
    float* psy2 = psx2 + NWAV * 64;
    float* psar = psy2 + NWAV * 64;
    unsigned long long* psk = (unsigned long long*)(psar + NWAV * 64);
    int W = blk * NWAV + wid;
    int wb = wid << 6;
    for (int T = W; T < NT; T += NBLKM * NWAV) {
      float Rf = (float)rows;
      float disc = (2.0f * Rf + 1.0f) * (2.0f * Rf + 1.0f) - 8.0f * (float)T;
      disc = disc > 0.0f ? disc : 0.0f;
      int by = (int)(((2.0f * Rf + 1.0f) - sqrtf(disc)) * 0.5f);
      if (by < 0) by = 0;
      if (by > rows - 1) by = rows - 1;
      while (by > 0 && T < by * rows - (by * (by - 1)) / 2) --by;
      while (by < rows - 1 && T >= (by + 1) * rows - ((by + 1) * by) / 2) ++by;
      int cum = by * rows - (by * (by - 1)) / 2;
      int bx = by + (T - cum);
      int i = by * 64 + lane;
      int j0 = bx * 64 + lane;
      float cx1 = x1a[j0], cy1 = y1a[j0], cx2 = x2a[j0], cy2 = y2a[j0];
      psx1[wb + lane] = cx1; psy1[wb + lane] = cy1;
      psx2[wb + lane] = cx2; psy2[wb + lane] = cy2;
      psar[wb + lane] = fmaxf(cx2 - cx1, 0.0f) * fmaxf(cy2 - cy1, 0.0f);
      psk[wb + lane] = skg[j0];
      float x1i = x1a[i], y1i = y1a[i], x2i = x2a[i], y2i = y2a[i];
      unsigned long long rk = skg[i];
      float ari = fmaxf(x2i - x1i, 0.0f) * fmaxf(y2i - y1i, 0.0f);
      unsigned long long w = 0ull;
      #pragma unroll 8
      for (int jj = 0; jj < 64; ++jj) {
        int j = bx * 64 + jj;
        float iw = fmaxf(fminf(x2i, psx2[wb + jj]) - fmaxf(x1i, psx1[wb + jj]), 0.0f);
        float ih = fmaxf(fminf(y2i, psy2[wb + jj]) - fmaxf(y1i, psy1[wb + jj]), 0.0f);
        float inter = iw * ih;
        float den = ((ari + psar[wb + jj]) - inter) + 1e-8f;  // exact ref op order
        float iou = inter / den;
        if ((iou > 0.5f) && (j > i)) w |= (1ull << jj);
      }
      while (__ballot(w != 0ull)) {
        bool tk = (w != 0ull);
        uint32_t pr = 0;
        if (tk) {
          int b = __builtin_ctzll(w); w &= w - 1;
          int j = bx * 64 + b;
          bool i_sup = (rk < psk[wb + b]);  // smaller key suppresses
          pr = i_sup ? (((uint32_t)i << 16) | (uint32_t)j)
                     : (((uint32_t)j << 16) | (uint32_t)i);
        }
        wave_compact32(tk, pr, paircnt, pairs, (uint32_t)PCAP);
      }
    }
  }

  // ---- one-way join: blocks != 0 signal and exit; block 0 waits (deadlock-free) ----
  __syncthreads();
  if (blk != 0) {
    if (tid == 0) {
      __threadfence();  // release this block's pair writes
      __hip_atomic_store(&flags2[blk], 1u, __ATOMIC_RELAXED, __HIP_MEMORY_SCOPE_AGENT);
    }
    return;
  }
  if (tid >= 1 && tid < NBLKM) {
    while (!__hip_atomic_load(&flags2[tid], __ATOMIC_RELAXED, __HIP_MEMORY_SCOPE_AGENT))
      __builtin_amdgcn_s_sleep(2);
  }
  __syncthreads();
  if (tid == 0) __threadfence();  // acquire: invalidate stale lines
  __syncthreads();

  // ---- phase F (block 0): exact top-4096 cut + Jacobi + top-500 emit ----
  uint32_t np = __hip_atomic_load(paircnt, __ATOMIC_RELAXED, __HIP_MEMORY_SCOPE_AGENT);
  if (np > (uint32_t)PCAP) np = (uint32_t)PCAP;
  for (int t = tid; t < KPOST * 6; t += 1024) out[t] = 0.0f;
  if (tid < 512) kkbuf[tid] = ~0ull;
  for (int t = tid; t < GCAP; t += 1024) lk[t] = (t < (int)gc) ? skg[t] : ~0ull;
  bool plds = (np <= (uint32_t)LPC);
  if (plds) for (uint32_t p = (uint32_t)tid; p < np; p += 1024) lpair[p] = pairs[p];
  if (tid == 0) { orlo = 0; orhi = 0; andlo = ~0u; andhi = ~0u; scnt2 = 0; }
  __syncthreads();

  uint32_t need1 = (gc < (uint32_t)KPRE) ? gc : (uint32_t)KPRE;
  if (need1 == 0) return;
  {
    unsigned long long myor = 0ull, myand = ~0ull;
    for (int t = tid; t < (int)gc; t += 1024) {
      unsigned long long k = lk[t];
      myor |= k; myand &= k;
    }
    #pragma unroll
    for (int d = 1; d < 64; d <<= 1) { myor |= shflx64(myor, d); myand &= shflx64(myand, d); }
    if (lane == 0) {
      atomicOr(&orlo, (uint32_t)myor); atomicOr(&orhi, (uint32_t)(myor >> 32));
      atomicAnd(&andlo, (uint32_t)myand); atomicAnd(&andhi, (uint32_t)(myand >> 32));
    }
  }
  __syncthreads();
  unsigned long long T1;
  {
    unsigned long long vor = ((unsigned long long)orhi << 32) | orlo;
    unsigned long long vand = ((unsigned long long)andhi << 32) | andlo;
    unsigned long long diff = vor ^ vand;
    unsigned long long pre = 0;
    uint32_t need = need1;
    for (int b = 7; b >= 0; --b) {
      uint32_t db = (uint32_t)(diff >> (8 * b)) & 255u;
      if (db == 0) { pre = (pre << 8) | ((uint32_t)(vand >> (8 * b)) & 255u); continue; }
      if (tid < 256) hsel[tid] = 0;
      __syncthreads();
      for (int t = tid; t < (int)gc; t += 1024) {
        unsigned long long k = lk[t];
        bool pm = (b == 7) ? true : ((k >> (8 * b + 8)) == pre);
        if (pm) atomicAdd(&hsel[(uint32_t)(k >> (8 * b)) & 255u], 1u);
      }
      __syncthreads();
      if (tid < 64) {
        uint32_t c0 = hsel[4 * tid], c1 = hsel[4 * tid + 1],
                 c2 = hsel[4 * tid + 2], c3 = hsel[4 * tid + 3];
        uint32_t s = c0 + c1 + c2 + c3;
        uint32_t p = s;
        #pragma unroll
        for (int d = 1; d < 64; d <<= 1) {
          uint32_t v = __shfl_up(p, d, 64);
          if (tid >= d) p += v;
        }
        uint32_t e0 = p - s, e1 = e0 + c0, e2 = e1 + c1, e3 = e2 + c2, e4 = e3 + c3;
        uint32_t eb[5] = {e0, e1, e2, e3, e4};
        #pragma unroll
        for (int q = 0; q < 4; ++q)
          if (eb[q] < need && need <= eb[q + 1]) {
            spre = (pre << 8) | (uint32_t)(4 * tid + q);
            sneedS = need - eb[q];
          }
      }
      __syncthreads();
      pre = spre; need = sneedS;
      __syncthreads();
    }
    T1 = pre;
  }

  for (int t = tid; t < GCAP; t += 1024) {
    unsigned long long k = lk[t];
    float v = ord2f(~(uint32_t)(k >> 32));
    bool ok = (k <= T1) && (v >= 0.1f);
    unsigned long long bm = __ballot(ok);
    if (lane == 0) { validm[t >> 6] = bm; accm[t >> 6] = bm; }
  }
  __syncthreads();

  while (true) {
    __syncthreads();
    if (tid < NMW * 2) supp[tid] = 0;
    if (tid == 0) chg = 0;
    __syncthreads();
    if (plds) {
      for (uint32_t p = (uint32_t)tid; p < np; p += 1024) {
        uint32_t pr = lpair[p];
        uint32_t i = pr >> 16, j = pr & 0xffffu;
        if ((accm[i >> 6] >> (i & 63)) & 1ull) atomicOr(&supp[j >> 5], 1u << (j & 31));
      }
    } else {
      for (uint32_t p = (uint32_t)tid; p < np; p += 1024) {
        uint32_t pr = pairs[p];
        uint32_t i = pr >> 16, j = pr & 0xffffu;
        if ((accm[i >> 6] >> (i & 63)) & 1ull) atomicOr(&supp[j >> 5], 1u << (j & 31));
      }
    }
    __syncthreads();
    if (tid < NMW) {
      unsigned long long s = ((unsigned long long)supp[2 * tid + 1] << 32) | supp[2 * tid];
      unsigned long long na = validm[tid] & ~s;
      if (na != accm[tid]) { accm[tid] = na; atomicOr(&chg, 1u); }
    }
    __syncthreads();
    if (chg == 0) break;
  }

  if (tid == 0) {
    uint32_t ns = 0;
    for (int l = 0; l < NMW; ++l) ns += (uint32_t)__builtin_popcountll(accm[l]);
    sneedS = (ns < (uint32_t)KPOST) ? ns : (uint32_t)KPOST;
    orlo = 0; orhi = 0; andlo = ~0u; andhi = ~0u;
  }
  __syncthreads();
  uint32_t need0 = sneedS;
  if (need0 == 0) return;
  {
    unsigned long long myor = 0ull, myand = ~0ull;
    for (int t = tid; t < GCAP; t += 1024) {
      if ((accm[t >> 6] >> (t & 63)) & 1ull) {
        unsigned long long k = lk[t];
        myor |= k; myand &= k;
      }
    }
    #pragma unroll
    for (int d = 1; d < 64; d <<= 1) { myor |= shflx64(myor, d); myand &= shflx64(myand, d); }
    if (lane == 0) {
      atomicOr(&orlo, (uint32_t)myor); atomicOr(&orhi, (uint32_t)(myor >> 32));
      atomicAnd(&andlo, (uint32_t)myand); atomicAnd(&andhi, (uint32_t)(myand >> 32));
    }
  }
  __syncthreads();
  unsigned long long T2;
  {
    unsigned long long vor = ((unsigned long long)orhi << 32) | orlo;
    unsigned long long vand = ((unsigned long long)andhi << 32) | andlo;
    unsigned long long diff = vor ^ vand;
    unsigned long long pre = 0;
    uint32_t need = need0;
    for (int b = 7; b >= 0; --b) {
      uint32_t db = (uint32_t)(diff >> (8 * b)) & 255u;
      if (db == 0) { pre = (pre << 8) | ((uint32_t)(vand >> (8 * b)) & 255u); continue; }
      if (tid < 256) hsel[tid] = 0;
      __syncthreads();
      for (int t = tid; t < GCAP; t += 1024) {
        if ((accm[t >> 6] >> (t & 63)) & 1ull) {
          unsigned long long k = lk[t];
          bool pm = (b == 7) ? true : ((k >> (8 * b + 8)) == pre);
          if (pm) atomicAdd(&hsel[(uint32_t)(k >> (8 * b)) & 255u], 1u);
        }
      }
      __syncthreads();
      if (tid < 64) {
        uint32_t c0 = hsel[4 * tid], c1 = hsel[4 * tid + 1],
                 c2 = hsel[4 * tid + 2], c3 = hsel[4 * tid + 3];
        uint32_t s = c0 + c1 + c2 + c3;
        uint32_t p = s;
        #pragma unroll
        for (int d = 1; d < 64; d <<= 1) {
          uint32_t v = __shfl_up(p, d, 64);
          if (tid >= d) p += v;
        }
        uint32_t e0 = p - s, e1 = e0 + c0, e2 = e1 + c1, e3 = e2 + c2, e4 = e3 + c3;
        uint32_t eb[5] = {e0, e1, e2, e3, e4};
        #pragma unroll
        for (int q = 0; q < 4; ++q)
          if (eb[q] < need && need <= eb[q + 1]) {
            spre = (pre << 8) | (uint32_t)(4 * tid + q);
            sneedS = need - eb[q];
          }
      }
      __syncthreads();
      pre = spre; need = sneedS;
      __syncthreads();
    }
    T2 = pre;
  }

  for (int t = tid; t < GCAP; t += 1024) {
    bool take = ((accm[t >> 6] >> (t & 63)) & 1ull) && (lk[t] <= T2);
    wave_compact32(take, (uint32_t)t, &scnt2, lsel, 512u);
  }
  __syncthreads();
  uint32_t cnt = min(scnt2, 512u);
  if (tid < (int)cnt) kkbuf[tid] = lk[lsel[tid]];
  __syncthreads();
  if (tid < (int)cnt) {
    unsigned long long k0 = kkbuf[tid];
    uint32_t rank = 0;
    #pragma unroll 8
    for (uint32_t p = 0; p < 512u; ++p) rank += (kkbuf[p] < k0) ? 1u : 0u;
    if (rank < (uint32_t)KPOST) {
      int i = (int)lsel[tid];
      out[rank * 6 + 0] = x1a[i];
      out[rank * 6 + 1] = y1a[i];
      out[rank * 6 + 2] = x2a[i];
      out[rank * 6 + 3] = y2a[i];
      out[rank * 6 + 4] = vala[i];
      out[rank * 6 + 5] = (float)laba[i];
    }
  }
}

extern "C" void kernel_launch(void* const* d_in, const int* in_sizes, int n_in,
                              void* d_out, int out_size, void* d_ws, size_t ws_size,
                              hipStream_t stream) {
  const float* boxes = (const float*)d_in[0];
  const float* cls   = (const float*)d_in[1];
  float* out = (float*)d_out;
  char* ws = (char*)d_ws;

  uint32_t* keys = (uint32_t*)(ws + OFF_KEYS);
  uint32_t* pairs = (uint32_t*)(ws + OFF_PAIRS);
  float* x1a = (float*)(ws + OFF_ARR);
  float* y1a = x1a + GCAP;
  float* x2a = y1a + GCAP;
  float* y2a = x2a + GCAP;
  float* vala = y2a + GCAP;
  int* laba = (int*)(vala + GCAP);
  unsigned long long* skg = (unsigned long long*)(laba + GCAP);
  uint8_t* labs = (uint8_t*)(ws + OFF_LAB);
  uint32_t* zbase = (uint32_t*)(ws + OFF_ZERO);
  uint32_t* hist0 = zbase + ZW_HIST0;
  uint32_t* hist2 = zbase + ZW_HIST2;
  uint32_t* hist16 = zbase + ZW_HIST16;
  uint32_t* state = zbase + ZW_STATE;

  hipMemsetAsync(ws + OFF_ZERO, 0, ZERO_BYTES, stream);
  k_score<<<1024, 256, 0, stream>>>(cls, keys, labs, hist0, hist16);
  k_mid<<<NBLKM, 1024, 0, stream>>>(keys, boxes, labs, hist0, hist16, hist2, state,
                                    x1a, y1a, x2a, y2a, vala, laba, skg);
  k_tail<<<NBLKM, 1024, 0, stream>>>(state, pairs, x1a, y1a, x2a, y2a,
                                     vala, laba, skg, out);
}